// Round 12
// baseline (262.596 us; speedup 1.0000x reference)
//
#include <hip/hip_runtime.h>

#define NN 100000
#define NE 1600000
#define FI 128
#define FH 64
#define FO 40
#define NB ((NN + 255) / 256)   // 391 scan blocks
#define NXCD 8

typedef _Float16 f16;

// ---------------- Threefry-2x32, key = (0, 42) -----------------------------
__device__ __forceinline__ unsigned rotl32(unsigned v, unsigned r) {
    return (v << r) | (v >> (32u - r));
}

__device__ __forceinline__ void threefry_0_42(unsigned x0, unsigned x1,
                                              unsigned& o0, unsigned& o1) {
    const unsigned k0 = 0u, k1 = 42u;
    const unsigned k2 = 0x1BD11BDAu ^ k0 ^ k1;
    x0 += k0; x1 += k1;
#define TFR(r) { x0 += x1; x1 = rotl32(x1, r); x1 ^= x0; }
    TFR(13) TFR(15) TFR(26) TFR(6)   x0 += k1; x1 += k2 + 1u;
    TFR(17) TFR(29) TFR(16) TFR(24)  x0 += k2; x1 += k0 + 2u;
    TFR(13) TFR(15) TFR(26) TFR(6)   x0 += k0; x1 += k1 + 3u;
    TFR(17) TFR(29) TFR(16) TFR(24)  x0 += k1; x1 += k2 + 4u;
    TFR(13) TFR(15) TFR(26) TFR(6)   x0 += k2; x1 += k0 + 5u;
#undef TFR
    o0 = x0; o1 = x1;
}

// ---------------- degree count into XCD-private replicas -------------------
// Each wave counts into its own XCD's replica: counter lines never migrate
// across XCDs (the 56MB ping-pong writeback seen in R11's profile).
__global__ __launch_bounds__(256) void k_count(const int* __restrict__ ei,
                                               int* __restrict__ cntP,
                                               int* __restrict__ rank) {
    unsigned xcc;
    asm("s_getreg_b32 %0, hwreg(HW_REG_XCC_ID)" : "=s"(xcc));
    int p = (int)(xcc & (NXCD - 1));
    int* mycnt = cntP + (size_t)p * NN;
    int ptag = p << 28;
    int i = blockIdx.x * blockDim.x + threadIdx.x;
    int stride = gridDim.x * blockDim.x;
    for (; i < NE; i += stride) {
        int lr = atomicAdd(&mycnt[ei[NE + i]], 1);  // local-L2 fetch-add
        rank[i] = ptag | lr;
    }
}

// ---------------- scanA: fold replicas + block scan ------------------------
__global__ __launch_bounds__(256) void k_scanA(const int* __restrict__ cntP,
                                               int* __restrict__ cnt,
                                               int* __restrict__ pre,
                                               int* __restrict__ offs,
                                               int* __restrict__ bsum) {
    __shared__ int sh[256];
    int t = threadIdx.x, g = blockIdx.x * 256 + t;
    int v = 0;
    if (g < NN) {
        int run = 0;
#pragma unroll
        for (int p = 0; p < NXCD; ++p) {
            pre[p * NN + g] = run;            // replica-prefix within dst
            run += cntP[p * NN + g];
        }
        v = run;
        cnt[g] = run;
    }
    sh[t] = v;
    __syncthreads();
    for (int off = 1; off < 256; off <<= 1) {
        int u = (t >= off) ? sh[t - off] : 0;
        __syncthreads();
        sh[t] += u;
        __syncthreads();
    }
    if (g < NN) offs[g] = sh[t] - v;               // exclusive within block
    if (t == 255) bsum[blockIdx.x] = sh[255];      // block total
}

__global__ __launch_bounds__(512) void k_scanB(int* __restrict__ bsum) {
    __shared__ int sh[512];
    int t = threadIdx.x;
    int v = (t < NB) ? bsum[t] : 0;
    sh[t] = v;
    __syncthreads();
    for (int off = 1; off < 512; off <<= 1) {
        int u = (t >= off) ? sh[t - off] : 0;
        __syncthreads();
        sh[t] += u;
        __syncthreads();
    }
    if (t < NB) bsum[t] = sh[t] - v;               // exclusive block offsets
}

// scanC: finalize offs, pack (offs,cnt) for agg, compute inv
__global__ __launch_bounds__(256) void k_scanC(int* __restrict__ offs,
                                               const int* __restrict__ bsum,
                                               const int* __restrict__ cnt,
                                               int2* __restrict__ odpk,
                                               float* __restrict__ inv) {
    int g = blockIdx.x * 256 + threadIdx.x;
    if (g < NN) {
        int o = offs[g] + bsum[blockIdx.x];
        offs[g] = o;
        int c = cnt[g];
        odpk[g] = make_int2(o, c);
        inv[g] = rsqrtf((float)c + 1.0f);
    }
}

// ---------------- CSR fill: pos = offs[d] + pre[p][d] + local_rank ---------
__global__ __launch_bounds__(256) void k_fill(const int* __restrict__ ei,
                                              const int* __restrict__ rank,
                                              const int* __restrict__ offs,
                                              const int* __restrict__ pre,
                                              int* __restrict__ csr_s) {
    int i = blockIdx.x * blockDim.x + threadIdx.x;
    int stride = gridDim.x * blockDim.x;
    for (; i < NE; i += stride) {
        int s = ei[i];
        int d = ei[NE + i];
        int r = rank[i];
        int p = ((unsigned)r) >> 28;
        int lr = r & 0x0FFFFFFF;
        csr_s[offs[d] + pre[p * NN + d] + lr] = s;
    }
}

// ---------------- GEMM1: h0s[N,64] = (x[N,128] @ W1) * inv[row]  (fp16) ----
#define XS_STRIDE 132   // 128 + 4: keeps b128 16B-aligned; rows on distinct banks
__global__ __launch_bounds__(256) void k_gemm1(const float* __restrict__ x,
                                               const float* __restrict__ W1,
                                               const float* __restrict__ inv,
                                               f16* __restrict__ h0s) {
    __shared__ float xs[64 * XS_STRIDE];   // 33.8 KB
    __shared__ float ws[64 * FH];          // 16 KB (one K-half of W1)
    int t = threadIdx.x;
    int row0 = blockIdx.x * 64;
    {
        int r = t >> 5;              // 0..7
        int c4 = (t & 31) * 4;       // 0..124
#pragma unroll
        for (int p = 0; p < 8; ++p) {
            int row = row0 + r + p * 8;
            float4 v = make_float4(0.f, 0.f, 0.f, 0.f);
            if (row < NN) v = *(const float4*)&x[(size_t)row * FI + c4];
            *(float4*)&xs[(r + p * 8) * XS_STRIDE + c4] = v;
        }
    }
    float acc[4][4] = {{0.f}};
    int tx4 = (t & 15) * 4;
    int ty4 = (t >> 4) * 4;
#pragma unroll
    for (int half = 0; half < 2; ++half) {
        __syncthreads();
        {
            const float4* Wv = (const float4*)(W1 + half * 64 * FH);
            float4* wv = (float4*)ws;
            for (int i = t; i < 64 * FH / 4; i += 256) wv[i] = Wv[i];
        }
        __syncthreads();
#pragma unroll 2
        for (int k = 0; k < 64; k += 4) {
            float4 a0 = *(const float4*)&xs[(ty4 + 0) * XS_STRIDE + half * 64 + k];
            float4 a1 = *(const float4*)&xs[(ty4 + 1) * XS_STRIDE + half * 64 + k];
            float4 a2 = *(const float4*)&xs[(ty4 + 2) * XS_STRIDE + half * 64 + k];
            float4 a3 = *(const float4*)&xs[(ty4 + 3) * XS_STRIDE + half * 64 + k];
            float4 b0 = *(const float4*)&ws[(k + 0) * FH + tx4];
            float4 b1 = *(const float4*)&ws[(k + 1) * FH + tx4];
            float4 b2 = *(const float4*)&ws[(k + 2) * FH + tx4];
            float4 b3 = *(const float4*)&ws[(k + 3) * FH + tx4];
#define KK1(AE, BV) \
            acc[0][0] = fmaf(a0.AE, BV.x, acc[0][0]); \
            acc[0][1] = fmaf(a0.AE, BV.y, acc[0][1]); \
            acc[0][2] = fmaf(a0.AE, BV.z, acc[0][2]); \
            acc[0][3] = fmaf(a0.AE, BV.w, acc[0][3]); \
            acc[1][0] = fmaf(a1.AE, BV.x, acc[1][0]); \
            acc[1][1] = fmaf(a1.AE, BV.y, acc[1][1]); \
            acc[1][2] = fmaf(a1.AE, BV.z, acc[1][2]); \
            acc[1][3] = fmaf(a1.AE, BV.w, acc[1][3]); \
            acc[2][0] = fmaf(a2.AE, BV.x, acc[2][0]); \
            acc[2][1] = fmaf(a2.AE, BV.y, acc[2][1]); \
            acc[2][2] = fmaf(a2.AE, BV.z, acc[2][2]); \
            acc[2][3] = fmaf(a2.AE, BV.w, acc[2][3]); \
            acc[3][0] = fmaf(a3.AE, BV.x, acc[3][0]); \
            acc[3][1] = fmaf(a3.AE, BV.y, acc[3][1]); \
            acc[3][2] = fmaf(a3.AE, BV.z, acc[3][2]); \
            acc[3][3] = fmaf(a3.AE, BV.w, acc[3][3]);
            KK1(x, b0) KK1(y, b1) KK1(z, b2) KK1(w, b3)
#undef KK1
        }
    }
#pragma unroll
    for (int i = 0; i < 4; ++i) {
        int row = row0 + ty4 + i;
        if (row < NN) {
            float s = inv[row];
            union { f16 h[4]; uint2 u; } p;
            p.h[0] = (f16)(acc[i][0] * s);
            p.h[1] = (f16)(acc[i][1] * s);
            p.h[2] = (f16)(acc[i][2] * s);
            p.h[3] = (f16)(acc[i][3] * s);
            *(uint2*)&h0s[(size_t)row * FH + tx4] = p.u;
        }
    }
}

// ---------------- agg1: gather(fp16) + self + bias + relu + dropout --------
__global__ __launch_bounds__(256) void k_agg1(const int2* __restrict__ odpk,
                                              const int* __restrict__ csr_s,
                                              const float* __restrict__ inv,
                                              const f16* __restrict__ h0s,
                                              const float* __restrict__ b1,
                                              float* __restrict__ h1) {
    int lane = threadIdx.x & 63;
    int d = __builtin_amdgcn_readfirstlane((int)(blockIdx.x * 4 + (threadIdx.x >> 6)));
    if (d >= NN) return;
    int2 od = odpk[d];
    int start = od.x, deg = od.y;
    float acc0 = 0.f, acc1 = 0.f;
    int k = 0;
    for (; k + 4 <= deg; k += 4) {
        int s0 = csr_s[start + k + 0];
        int s1 = csr_s[start + k + 1];
        int s2 = csr_s[start + k + 2];
        int s3 = csr_s[start + k + 3];
        float v0 = (float)h0s[(size_t)s0 * FH + lane];
        float v1 = (float)h0s[(size_t)s1 * FH + lane];
        float v2 = (float)h0s[(size_t)s2 * FH + lane];
        float v3 = (float)h0s[(size_t)s3 * FH + lane];
        acc0 += v0 + v2;
        acc1 += v1 + v3;
    }
    for (; k < deg; ++k) {
        int s = csr_s[start + k];
        acc0 += (float)h0s[(size_t)s * FH + lane];
    }
    float invd = inv[d];
    float val = (acc0 + acc1 + (float)h0s[(size_t)d * FH + lane]) * invd + b1[lane];
    val = fmaxf(val, 0.f);
    int i = d * FH + lane;
    unsigned o0, o1;
    threefry_0_42(0u, (unsigned)i, o0, o1);
    unsigned wbits = o0 ^ o1;            // partitionable f32 path: XOR fold
    h1[i] = (wbits >> 31) ? 0.f : val * 2.f;
}

// ---------------- GEMM2: h2s[N,64(pad)] = (h1 @ W2) * inv[row]  (fp16) -----
#define HS_STRIDE 68    // 64 + 4: b128-aligned, rows on distinct banks
__global__ __launch_bounds__(256) void k_gemm2(const float* __restrict__ h,
                                               const float* __restrict__ W2,
                                               const float* __restrict__ inv,
                                               f16* __restrict__ h2s) {
    __shared__ float hs[64 * HS_STRIDE];   // 17.4 KB
    __shared__ float ws[FH * 64];          // 16 KB, cols 40..63 zero
    int t = threadIdx.x;
    int row0 = blockIdx.x * 64;
    {
        int r = t >> 4;              // 0..15
        int c4 = (t & 15) * 4;       // 0..60
#pragma unroll
        for (int p = 0; p < 4; ++p) {
            int row = row0 + r + p * 16;
            float4 v = make_float4(0.f, 0.f, 0.f, 0.f);
            if (row < NN) v = *(const float4*)&h[(size_t)row * FH + c4];
            *(float4*)&hs[(r + p * 16) * HS_STRIDE + c4] = v;
        }
    }
    for (int i = t; i < FH * 64; i += 256) {
        int r = i >> 6, c = i & 63;
        ws[i] = (c < FO) ? W2[r * FO + c] : 0.f;
    }
    __syncthreads();
    float acc[4][4] = {{0.f}};
    int tx4 = (t & 15) * 4;
    int ty4 = (t >> 4) * 4;
#pragma unroll 2
    for (int k = 0; k < FH; k += 4) {
        float4 a0 = *(const float4*)&hs[(ty4 + 0) * HS_STRIDE + k];
        float4 a1 = *(const float4*)&hs[(ty4 + 1) * HS_STRIDE + k];
        float4 a2 = *(const float4*)&hs[(ty4 + 2) * HS_STRIDE + k];
        float4 a3 = *(const float4*)&hs[(ty4 + 3) * HS_STRIDE + k];
        float4 b0 = *(const float4*)&ws[(k + 0) * 64 + tx4];
        float4 b1 = *(const float4*)&ws[(k + 1) * 64 + tx4];
        float4 b2 = *(const float4*)&ws[(k + 2) * 64 + tx4];
        float4 b3 = *(const float4*)&ws[(k + 3) * 64 + tx4];
#define KK2(AE, BV) \
        acc[0][0] = fmaf(a0.AE, BV.x, acc[0][0]); \
        acc[0][1] = fmaf(a0.AE, BV.y, acc[0][1]); \
        acc[0][2] = fmaf(a0.AE, BV.z, acc[0][2]); \
        acc[0][3] = fmaf(a0.AE, BV.w, acc[0][3]); \
        acc[1][0] = fmaf(a1.AE, BV.x, acc[1][0]); \
        acc[1][1] = fmaf(a1.AE, BV.y, acc[1][1]); \
        acc[1][2] = fmaf(a1.AE, BV.z, acc[1][2]); \
        acc[1][3] = fmaf(a1.AE, BV.w, acc[1][3]); \
        acc[2][0] = fmaf(a2.AE, BV.x, acc[2][0]); \
        acc[2][1] = fmaf(a2.AE, BV.y, acc[2][1]); \
        acc[2][2] = fmaf(a2.AE, BV.z, acc[2][2]); \
        acc[2][3] = fmaf(a2.AE, BV.w, acc[2][3]); \
        acc[3][0] = fmaf(a3.AE, BV.x, acc[3][0]); \
        acc[3][1] = fmaf(a3.AE, BV.y, acc[3][1]); \
        acc[3][2] = fmaf(a3.AE, BV.z, acc[3][2]); \
        acc[3][3] = fmaf(a3.AE, BV.w, acc[3][3]);
        KK2(x, b0) KK2(y, b1) KK2(z, b2) KK2(w, b3)
#undef KK2
    }
#pragma unroll
    for (int i = 0; i < 4; ++i) {
        int row = row0 + ty4 + i;
        if (row < NN) {
            float s = inv[row];
            union { f16 h[4]; uint2 u; } p;
            p.h[0] = (f16)(acc[i][0] * s);
            p.h[1] = (f16)(acc[i][1] * s);
            p.h[2] = (f16)(acc[i][2] * s);
            p.h[3] = (f16)(acc[i][3] * s);
            *(uint2*)&h2s[(size_t)row * FH + tx4] = p.u;
        }
    }
}

// ---------------- agg2: gather(fp16) + self + b2 -> out --------------------
__global__ __launch_bounds__(256) void k_agg2(const int2* __restrict__ odpk,
                                              const int* __restrict__ csr_s,
                                              const float* __restrict__ inv,
                                              const f16* __restrict__ h2s,
                                              const float* __restrict__ b2,
                                              float* __restrict__ out) {
    int lane = threadIdx.x & 63;
    int d = __builtin_amdgcn_readfirstlane((int)(blockIdx.x * 4 + (threadIdx.x >> 6)));
    if (d >= NN) return;
    int2 od = odpk[d];
    int start = od.x, deg = od.y;
    float acc0 = 0.f, acc1 = 0.f;
    int k = 0;
    for (; k + 4 <= deg; k += 4) {
        int s0 = csr_s[start + k + 0];
        int s1 = csr_s[start + k + 1];
        int s2 = csr_s[start + k + 2];
        int s3 = csr_s[start + k + 3];
        float v0 = (float)h2s[(size_t)s0 * FH + lane];
        float v1 = (float)h2s[(size_t)s1 * FH + lane];
        float v2 = (float)h2s[(size_t)s2 * FH + lane];
        float v3 = (float)h2s[(size_t)s3 * FH + lane];
        acc0 += v0 + v2;
        acc1 += v1 + v3;
    }
    for (; k < deg; ++k) {
        int s = csr_s[start + k];
        acc0 += (float)h2s[(size_t)s * FH + lane];
    }
    if (lane < FO) {
        float invd = inv[d];
        out[(size_t)d * FO + lane] =
            (acc0 + acc1 + (float)h2s[(size_t)d * FH + lane]) * invd + b2[lane];
    }
}

extern "C" void kernel_launch(void* const* d_in, const int* in_sizes, int n_in,
                              void* d_out, int out_size, void* d_ws, size_t ws_size,
                              hipStream_t stream) {
    const float* x  = (const float*)d_in[0];
    const int*   ei = (const int*)d_in[1];   // int32 [2, NE]: src = ei[e], dst = ei[NE+e]
    const float* W1 = (const float*)d_in[2];
    const float* b1 = (const float*)d_in[3];
    const float* W2 = (const float*)d_in[4];
    const float* b2 = (const float*)d_in[5];
    float* out = (float*)d_out;

    char* ws = (char*)d_ws;
    int*   cntP  = (int*)ws;                              // 3.2 MB (8 replicas)
    int*   cnt   = (int*)(ws + (size_t)( 4 << 20));       // 0.4 MB
    int*   offs  = (int*)(ws + (size_t)( 5 << 20));       // 0.4 MB
    int*   bsum  = (int*)(ws + (size_t)( 6 << 20));       // 1.6 KB
    float* inv   = (float*)(ws + (size_t)( 7 << 20));     // 0.4 MB
    int2*  odpk  = (int2*)(ws + (size_t)( 8 << 20));      // 0.8 MB
    int*   pre   = (int*)(ws + (size_t)( 9 << 20));       // 3.2 MB
    int*   rank  = (int*)(ws + (size_t)(13 << 20));       // 6.4 MB (free after fill)
    f16*   h2s   = (f16*)(ws + (size_t)(13 << 20));       // 12.8 MB (reuses rank)
    int*   csr_s = (int*)(ws + (size_t)(26 << 20));       // 6.4 MB
    f16*   h0s   = (f16*)(ws + (size_t)(33 << 20));       // 12.8 MB
    float* h1    = (float*)(ws + (size_t)(46 << 20));     // 25.6 MB

    hipMemsetAsync(cntP, 0, (size_t)NXCD * NN * sizeof(int), stream);

    k_count<<<2048, 256, 0, stream>>>(ei, cntP, rank);
    k_scanA<<<NB, 256, 0, stream>>>(cntP, cnt, pre, offs, bsum);
    k_scanB<<<1, 512, 0, stream>>>(bsum);
    k_scanC<<<NB, 256, 0, stream>>>(offs, bsum, cnt, odpk, inv);
    k_fill<<<2048, 256, 0, stream>>>(ei, rank, offs, pre, csr_s);

    int gblk = (NN + 63) / 64;   // 1563
    k_gemm1<<<gblk, 256, 0, stream>>>(x, W1, inv, h0s);
    k_agg1<<<NN / 4, 256, 0, stream>>>(odpk, csr_s, inv, h0s, b1, h1);

    k_gemm2<<<gblk, 256, 0, stream>>>(h1, W2, inv, h2s);
    k_agg2<<<NN / 4, 256, 0, stream>>>(odpk, csr_s, inv, h2s, b2, out);
}

// Round 13
// 202.590 us; speedup vs baseline: 1.2962x; 1.2962x over previous
//
#include <hip/hip_runtime.h>

#define NN 100000
#define NE 1600000
#define FI 128
#define FH 64
#define FO 40
#define NR 500      // dst ranges
#define RSZ 200     // nodes per range (NR*RSZ == NN)
#define NBK 512     // histogram/scatter blocks

typedef _Float16 f16;

// ---------------- Threefry-2x32, key = (0, 42) -----------------------------
__device__ __forceinline__ unsigned rotl32(unsigned v, unsigned r) {
    return (v << r) | (v >> (32u - r));
}

__device__ __forceinline__ void threefry_0_42(unsigned x0, unsigned x1,
                                              unsigned& o0, unsigned& o1) {
    const unsigned k0 = 0u, k1 = 42u;
    const unsigned k2 = 0x1BD11BDAu ^ k0 ^ k1;
    x0 += k0; x1 += k1;
#define TFR(r) { x0 += x1; x1 = rotl32(x1, r); x1 ^= x0; }
    TFR(13) TFR(15) TFR(26) TFR(6)   x0 += k1; x1 += k2 + 1u;
    TFR(17) TFR(29) TFR(16) TFR(24)  x0 += k2; x1 += k0 + 2u;
    TFR(13) TFR(15) TFR(26) TFR(6)   x0 += k0; x1 += k1 + 3u;
    TFR(17) TFR(29) TFR(16) TFR(24)  x0 += k1; x1 += k2 + 4u;
    TFR(13) TFR(15) TFR(26) TFR(6)   x0 += k2; x1 += k0 + 5u;
#undef TFR
    o0 = x0; o1 = x1;
}

// ---------------- P1: per-block LDS range histogram ------------------------
__global__ __launch_bounds__(256) void k_p1(const int* __restrict__ ei,
                                            int* __restrict__ blkhist) {
    __shared__ int h[NR];
    int t = threadIdx.x, b = blockIdx.x;
    for (int i = t; i < NR; i += 256) h[i] = 0;
    __syncthreads();
    for (int i = b * 256 + t; i < NE; i += NBK * 256) {
        int d = ei[NE + i];
        atomicAdd(&h[d / RSZ], 1);               // LDS atomic
    }
    __syncthreads();
    for (int i = t; i < NR; i += 256) blkhist[(size_t)b * NR + i] = h[i];
}

// ---------------- scanR1: per-range exclusive scan over blocks -------------
__global__ __launch_bounds__(512) void k_scanR1(int* __restrict__ blkhist,
                                                int* __restrict__ rtot) {
    __shared__ int sh[NBK];
    int r = blockIdx.x, t = threadIdx.x;
    int v = blkhist[(size_t)t * NR + r];
    sh[t] = v;
    __syncthreads();
    for (int off = 1; off < NBK; off <<= 1) {
        int u = (t >= off) ? sh[t - off] : 0;
        __syncthreads();
        sh[t] += u;
        __syncthreads();
    }
    blkhist[(size_t)t * NR + r] = sh[t] - v;     // block-local prefix
    if (t == NBK - 1) rtot[r] = sh[t];
}

// ---------------- scanR2: exclusive scan of range totals -------------------
__global__ __launch_bounds__(512) void k_scanR2(const int* __restrict__ rtot,
                                                int* __restrict__ rangeBase) {
    __shared__ int sh[512];
    int t = threadIdx.x;
    int v = (t < NR) ? rtot[t] : 0;
    sh[t] = v;
    __syncthreads();
    for (int off = 1; off < 512; off <<= 1) {
        int u = (t >= off) ? sh[t - off] : 0;
        __syncthreads();
        sh[t] += u;
        __syncthreads();
    }
    if (t < NR) rangeBase[t] = sh[t] - v;
    if (t == NR - 1) rangeBase[NR] = sh[t];      // == NE
}

// ---------------- P2: scatter edges into range buckets (LDS cursors) -------
__global__ __launch_bounds__(256) void k_p2(const int* __restrict__ ei,
                                            const int* __restrict__ blkhist,
                                            const int* __restrict__ rangeBase,
                                            int2* __restrict__ bucket) {
    __shared__ int cur[NR];
    int t = threadIdx.x, b = blockIdx.x;
    for (int i = t; i < NR; i += 256)
        cur[i] = rangeBase[i] + blkhist[(size_t)b * NR + i];
    __syncthreads();
    for (int i = b * 256 + t; i < NE; i += NBK * 256) {   // same slice as k_p1
        int s = ei[i];
        int d = ei[NE + i];
        int pos = atomicAdd(&cur[d / RSZ], 1);            // LDS atomic
        bucket[pos] = make_int2(s, d);
    }
}

// ---------------- P3: per-range CSR finalize (LDS count+scan+cursor) -------
__global__ __launch_bounds__(256) void k_p3(const int2* __restrict__ bucket,
                                            const int* __restrict__ rangeBase,
                                            int2* __restrict__ odpk,
                                            float* __restrict__ inv,
                                            int* __restrict__ csr_s) {
    __shared__ int cnt[RSZ];
    __shared__ int base[RSZ];
    __shared__ int sc[256];
    int r = blockIdx.x, t = threadIdx.x;
    int e0 = rangeBase[r], e1 = rangeBase[r + 1];
    int n0 = r * RSZ;
    if (t < RSZ) cnt[t] = 0;
    __syncthreads();
    for (int i = e0 + t; i < e1; i += 256)
        atomicAdd(&cnt[bucket[i].y - n0], 1);             // LDS atomic
    __syncthreads();
    int v = (t < RSZ) ? cnt[t] : 0;
    sc[t] = v;
    __syncthreads();
    for (int off = 1; off < 256; off <<= 1) {
        int u = (t >= off) ? sc[t - off] : 0;
        __syncthreads();
        sc[t] += u;
        __syncthreads();
    }
    if (t < RSZ) {
        int o = e0 + sc[t] - v;                           // global CSR offset
        odpk[n0 + t] = make_int2(o, v);
        inv[n0 + t] = rsqrtf((float)v + 1.0f);
        base[t] = o;                                      // cursor start
    }
    __syncthreads();
    for (int i = e0 + t; i < e1; i += 256) {
        int2 sd = bucket[i];
        int p = atomicAdd(&base[sd.y - n0], 1);           // LDS atomic
        csr_s[p] = sd.x;
    }
}

// ---------------- GEMM1: h0s[N,64] = (x[N,128] @ W1) * inv[row]  (fp16) ----
#define XS_STRIDE 132   // 128 + 4: keeps b128 16B-aligned; rows on distinct banks
__global__ __launch_bounds__(256) void k_gemm1(const float* __restrict__ x,
                                               const float* __restrict__ W1,
                                               const float* __restrict__ inv,
                                               f16* __restrict__ h0s) {
    __shared__ float xs[64 * XS_STRIDE];   // 33.8 KB
    __shared__ float ws[64 * FH];          // 16 KB (one K-half of W1)
    int t = threadIdx.x;
    int row0 = blockIdx.x * 64;
    {
        int r = t >> 5;              // 0..7
        int c4 = (t & 31) * 4;       // 0..124
#pragma unroll
        for (int p = 0; p < 8; ++p) {
            int row = row0 + r + p * 8;
            float4 v = make_float4(0.f, 0.f, 0.f, 0.f);
            if (row < NN) v = *(const float4*)&x[(size_t)row * FI + c4];
            *(float4*)&xs[(r + p * 8) * XS_STRIDE + c4] = v;
        }
    }
    float acc[4][4] = {{0.f}};
    int tx4 = (t & 15) * 4;
    int ty4 = (t >> 4) * 4;
#pragma unroll
    for (int half = 0; half < 2; ++half) {
        __syncthreads();
        {
            const float4* Wv = (const float4*)(W1 + half * 64 * FH);
            float4* wv = (float4*)ws;
            for (int i = t; i < 64 * FH / 4; i += 256) wv[i] = Wv[i];
        }
        __syncthreads();
#pragma unroll 2
        for (int k = 0; k < 64; k += 4) {
            float4 a0 = *(const float4*)&xs[(ty4 + 0) * XS_STRIDE + half * 64 + k];
            float4 a1 = *(const float4*)&xs[(ty4 + 1) * XS_STRIDE + half * 64 + k];
            float4 a2 = *(const float4*)&xs[(ty4 + 2) * XS_STRIDE + half * 64 + k];
            float4 a3 = *(const float4*)&xs[(ty4 + 3) * XS_STRIDE + half * 64 + k];
            float4 b0 = *(const float4*)&ws[(k + 0) * FH + tx4];
            float4 b1 = *(const float4*)&ws[(k + 1) * FH + tx4];
            float4 b2 = *(const float4*)&ws[(k + 2) * FH + tx4];
            float4 b3 = *(const float4*)&ws[(k + 3) * FH + tx4];
#define KK1(AE, BV) \
            acc[0][0] = fmaf(a0.AE, BV.x, acc[0][0]); \
            acc[0][1] = fmaf(a0.AE, BV.y, acc[0][1]); \
            acc[0][2] = fmaf(a0.AE, BV.z, acc[0][2]); \
            acc[0][3] = fmaf(a0.AE, BV.w, acc[0][3]); \
            acc[1][0] = fmaf(a1.AE, BV.x, acc[1][0]); \
            acc[1][1] = fmaf(a1.AE, BV.y, acc[1][1]); \
            acc[1][2] = fmaf(a1.AE, BV.z, acc[1][2]); \
            acc[1][3] = fmaf(a1.AE, BV.w, acc[1][3]); \
            acc[2][0] = fmaf(a2.AE, BV.x, acc[2][0]); \
            acc[2][1] = fmaf(a2.AE, BV.y, acc[2][1]); \
            acc[2][2] = fmaf(a2.AE, BV.z, acc[2][2]); \
            acc[2][3] = fmaf(a2.AE, BV.w, acc[2][3]); \
            acc[3][0] = fmaf(a3.AE, BV.x, acc[3][0]); \
            acc[3][1] = fmaf(a3.AE, BV.y, acc[3][1]); \
            acc[3][2] = fmaf(a3.AE, BV.z, acc[3][2]); \
            acc[3][3] = fmaf(a3.AE, BV.w, acc[3][3]);
            KK1(x, b0) KK1(y, b1) KK1(z, b2) KK1(w, b3)
#undef KK1
        }
    }
#pragma unroll
    for (int i = 0; i < 4; ++i) {
        int row = row0 + ty4 + i;
        if (row < NN) {
            float s = inv[row];
            union { f16 h[4]; uint2 u; } p;
            p.h[0] = (f16)(acc[i][0] * s);
            p.h[1] = (f16)(acc[i][1] * s);
            p.h[2] = (f16)(acc[i][2] * s);
            p.h[3] = (f16)(acc[i][3] * s);
            *(uint2*)&h0s[(size_t)row * FH + tx4] = p.u;
        }
    }
}

// ---------------- agg1: gather(fp16) + self + bias + relu + dropout --------
__global__ __launch_bounds__(256) void k_agg1(const int2* __restrict__ odpk,
                                              const int* __restrict__ csr_s,
                                              const float* __restrict__ inv,
                                              const f16* __restrict__ h0s,
                                              const float* __restrict__ b1,
                                              float* __restrict__ h1) {
    int lane = threadIdx.x & 63;
    int d = __builtin_amdgcn_readfirstlane((int)(blockIdx.x * 4 + (threadIdx.x >> 6)));
    if (d >= NN) return;
    int2 od = odpk[d];
    int start = od.x, deg = od.y;
    float acc0 = 0.f, acc1 = 0.f;
    int k = 0;
    for (; k + 4 <= deg; k += 4) {
        int s0 = csr_s[start + k + 0];
        int s1 = csr_s[start + k + 1];
        int s2 = csr_s[start + k + 2];
        int s3 = csr_s[start + k + 3];
        float v0 = (float)h0s[(size_t)s0 * FH + lane];
        float v1 = (float)h0s[(size_t)s1 * FH + lane];
        float v2 = (float)h0s[(size_t)s2 * FH + lane];
        float v3 = (float)h0s[(size_t)s3 * FH + lane];
        acc0 += v0 + v2;
        acc1 += v1 + v3;
    }
    for (; k < deg; ++k) {
        int s = csr_s[start + k];
        acc0 += (float)h0s[(size_t)s * FH + lane];
    }
    float invd = inv[d];
    float val = (acc0 + acc1 + (float)h0s[(size_t)d * FH + lane]) * invd + b1[lane];
    val = fmaxf(val, 0.f);
    int i = d * FH + lane;
    unsigned o0, o1;
    threefry_0_42(0u, (unsigned)i, o0, o1);
    unsigned wbits = o0 ^ o1;            // partitionable f32 path: XOR fold
    h1[i] = (wbits >> 31) ? 0.f : val * 2.f;
}

// ---------------- GEMM2: h2s[N,64(pad)] = (h1 @ W2) * inv[row]  (fp16) -----
#define HS_STRIDE 68    // 64 + 4: b128-aligned, rows on distinct banks
__global__ __launch_bounds__(256) void k_gemm2(const float* __restrict__ h,
                                               const float* __restrict__ W2,
                                               const float* __restrict__ inv,
                                               f16* __restrict__ h2s) {
    __shared__ float hs[64 * HS_STRIDE];   // 17.4 KB
    __shared__ float ws[FH * 64];          // 16 KB, cols 40..63 zero
    int t = threadIdx.x;
    int row0 = blockIdx.x * 64;
    {
        int r = t >> 4;              // 0..15
        int c4 = (t & 15) * 4;       // 0..60
#pragma unroll
        for (int p = 0; p < 4; ++p) {
            int row = row0 + r + p * 16;
            float4 v = make_float4(0.f, 0.f, 0.f, 0.f);
            if (row < NN) v = *(const float4*)&h[(size_t)row * FH + c4];
            *(float4*)&hs[(r + p * 16) * HS_STRIDE + c4] = v;
        }
    }
    for (int i = t; i < FH * 64; i += 256) {
        int r = i >> 6, c = i & 63;
        ws[i] = (c < FO) ? W2[r * FO + c] : 0.f;
    }
    __syncthreads();
    float acc[4][4] = {{0.f}};
    int tx4 = (t & 15) * 4;
    int ty4 = (t >> 4) * 4;
#pragma unroll 2
    for (int k = 0; k < FH; k += 4) {
        float4 a0 = *(const float4*)&hs[(ty4 + 0) * HS_STRIDE + k];
        float4 a1 = *(const float4*)&hs[(ty4 + 1) * HS_STRIDE + k];
        float4 a2 = *(const float4*)&hs[(ty4 + 2) * HS_STRIDE + k];
        float4 a3 = *(const float4*)&hs[(ty4 + 3) * HS_STRIDE + k];
        float4 b0 = *(const float4*)&ws[(k + 0) * 64 + tx4];
        float4 b1 = *(const float4*)&ws[(k + 1) * 64 + tx4];
        float4 b2 = *(const float4*)&ws[(k + 2) * 64 + tx4];
        float4 b3 = *(const float4*)&ws[(k + 3) * 64 + tx4];
#define KK2(AE, BV) \
        acc[0][0] = fmaf(a0.AE, BV.x, acc[0][0]); \
        acc[0][1] = fmaf(a0.AE, BV.y, acc[0][1]); \
        acc[0][2] = fmaf(a0.AE, BV.z, acc[0][2]); \
        acc[0][3] = fmaf(a0.AE, BV.w, acc[0][3]); \
        acc[1][0] = fmaf(a1.AE, BV.x, acc[1][0]); \
        acc[1][1] = fmaf(a1.AE, BV.y, acc[1][1]); \
        acc[1][2] = fmaf(a1.AE, BV.z, acc[1][2]); \
        acc[1][3] = fmaf(a1.AE, BV.w, acc[1][3]); \
        acc[2][0] = fmaf(a2.AE, BV.x, acc[2][0]); \
        acc[2][1] = fmaf(a2.AE, BV.y, acc[2][1]); \
        acc[2][2] = fmaf(a2.AE, BV.z, acc[2][2]); \
        acc[2][3] = fmaf(a2.AE, BV.w, acc[2][3]); \
        acc[3][0] = fmaf(a3.AE, BV.x, acc[3][0]); \
        acc[3][1] = fmaf(a3.AE, BV.y, acc[3][1]); \
        acc[3][2] = fmaf(a3.AE, BV.z, acc[3][2]); \
        acc[3][3] = fmaf(a3.AE, BV.w, acc[3][3]);
        KK2(x, b0) KK2(y, b1) KK2(z, b2) KK2(w, b3)
#undef KK2
    }
#pragma unroll
    for (int i = 0; i < 4; ++i) {
        int row = row0 + ty4 + i;
        if (row < NN) {
            float s = inv[row];
            union { f16 h[4]; uint2 u; } p;
            p.h[0] = (f16)(acc[i][0] * s);
            p.h[1] = (f16)(acc[i][1] * s);
            p.h[2] = (f16)(acc[i][2] * s);
            p.h[3] = (f16)(acc[i][3] * s);
            *(uint2*)&h2s[(size_t)row * FH + tx4] = p.u;
        }
    }
}

// ---------------- agg2: gather(fp16) + self + b2 -> out --------------------
__global__ __launch_bounds__(256) void k_agg2(const int2* __restrict__ odpk,
                                              const int* __restrict__ csr_s,
                                              const float* __restrict__ inv,
                                              const f16* __restrict__ h2s,
                                              const float* __restrict__ b2,
                                              float* __restrict__ out) {
    int lane = threadIdx.x & 63;
    int d = __builtin_amdgcn_readfirstlane((int)(blockIdx.x * 4 + (threadIdx.x >> 6)));
    if (d >= NN) return;
    int2 od = odpk[d];
    int start = od.x, deg = od.y;
    float acc0 = 0.f, acc1 = 0.f;
    int k = 0;
    for (; k + 4 <= deg; k += 4) {
        int s0 = csr_s[start + k + 0];
        int s1 = csr_s[start + k + 1];
        int s2 = csr_s[start + k + 2];
        int s3 = csr_s[start + k + 3];
        float v0 = (float)h2s[(size_t)s0 * FH + lane];
        float v1 = (float)h2s[(size_t)s1 * FH + lane];
        float v2 = (float)h2s[(size_t)s2 * FH + lane];
        float v3 = (float)h2s[(size_t)s3 * FH + lane];
        acc0 += v0 + v2;
        acc1 += v1 + v3;
    }
    for (; k < deg; ++k) {
        int s = csr_s[start + k];
        acc0 += (float)h2s[(size_t)s * FH + lane];
    }
    if (lane < FO) {
        float invd = inv[d];
        out[(size_t)d * FO + lane] =
            (acc0 + acc1 + (float)h2s[(size_t)d * FH + lane]) * invd + b2[lane];
    }
}

extern "C" void kernel_launch(void* const* d_in, const int* in_sizes, int n_in,
                              void* d_out, int out_size, void* d_ws, size_t ws_size,
                              hipStream_t stream) {
    const float* x  = (const float*)d_in[0];
    const int*   ei = (const int*)d_in[1];   // int32 [2, NE]: src = ei[e], dst = ei[NE+e]
    const float* W1 = (const float*)d_in[2];
    const float* b1 = (const float*)d_in[3];
    const float* W2 = (const float*)d_in[4];
    const float* b2 = (const float*)d_in[5];
    float* out = (float*)d_out;

    char* ws = (char*)d_ws;
    int*   blkhist   = (int*)ws;                              // 1.0 MB (512*500)
    int*   rtot      = (int*)(ws + (size_t)(1 << 20) + 102400);   // 2 KB
    int*   rangeBase = (int*)(ws + (size_t)(1 << 20) + 106496);   // 2 KB (501)
    float* inv       = (float*)(ws + (size_t)( 2 << 20));     // 0.4 MB
    int2*  odpk      = (int2*)(ws + (size_t)( 3 << 20));      // 0.8 MB
    int2*  bucket    = (int2*)(ws + (size_t)( 4 << 20));      // 12.8 MB (dead after p3)
    f16*   h2s       = (f16*)bucket;                          // 12.8 MB (reuses bucket)
    int*   csr_s     = (int*)(ws + (size_t)(17 << 20));       // 6.4 MB
    f16*   h0s       = (f16*)(ws + (size_t)(24 << 20));       // 12.8 MB
    float* h1        = (float*)(ws + (size_t)(37 << 20));     // 25.6 MB -> peak 62.6 MB

    k_p1<<<NBK, 256, 0, stream>>>(ei, blkhist);
    k_scanR1<<<NR, 512, 0, stream>>>(blkhist, rtot);
    k_scanR2<<<1, 512, 0, stream>>>(rtot, rangeBase);
    k_p2<<<NBK, 256, 0, stream>>>(ei, blkhist, rangeBase, bucket);
    k_p3<<<NR, 256, 0, stream>>>(bucket, rangeBase, odpk, inv, csr_s);

    int gblk = (NN + 63) / 64;   // 1563
    k_gemm1<<<gblk, 256, 0, stream>>>(x, W1, inv, h0s);
    k_agg1<<<NN / 4, 256, 0, stream>>>(odpk, csr_s, inv, h0s, b1, h1);

    k_gemm2<<<gblk, 256, 0, stream>>>(h1, W2, inv, h2s);
    k_agg2<<<NN / 4, 256, 0, stream>>>(odpk, csr_s, inv, h2s, b2, out);
}

// Round 14
// 192.369 us; speedup vs baseline: 1.3651x; 1.0531x over previous
//
#include <hip/hip_runtime.h>

#define NN 100000
#define NE 1600000
#define FI 128
#define FH 64
#define FO 40
#define NR 500      // dst ranges
#define RSZ 200     // nodes per range (NR*RSZ == NN)
#define NBK 512     // histogram/scatter blocks

typedef _Float16 f16;

// ---------------- Threefry-2x32, key = (0, 42) -----------------------------
__device__ __forceinline__ unsigned rotl32(unsigned v, unsigned r) {
    return (v << r) | (v >> (32u - r));
}

__device__ __forceinline__ void threefry_0_42(unsigned x0, unsigned x1,
                                              unsigned& o0, unsigned& o1) {
    const unsigned k0 = 0u, k1 = 42u;
    const unsigned k2 = 0x1BD11BDAu ^ k0 ^ k1;
    x0 += k0; x1 += k1;
#define TFR(r) { x0 += x1; x1 = rotl32(x1, r); x1 ^= x0; }
    TFR(13) TFR(15) TFR(26) TFR(6)   x0 += k1; x1 += k2 + 1u;
    TFR(17) TFR(29) TFR(16) TFR(24)  x0 += k2; x1 += k0 + 2u;
    TFR(13) TFR(15) TFR(26) TFR(6)   x0 += k0; x1 += k1 + 3u;
    TFR(17) TFR(29) TFR(16) TFR(24)  x0 += k1; x1 += k2 + 4u;
    TFR(13) TFR(15) TFR(26) TFR(6)   x0 += k2; x1 += k0 + 5u;
#undef TFR
    o0 = x0; o1 = x1;
}

__device__ __forceinline__ void unpack2(unsigned u, float& lo, float& hi) {
    union { unsigned u; f16 h[2]; } c;
    c.u = u;
    lo = (float)c.h[0];
    hi = (float)c.h[1];
}

// ---------------- P1: per-block LDS range histogram ------------------------
__global__ __launch_bounds__(256) void k_p1(const int* __restrict__ ei,
                                            int* __restrict__ blkhist) {
    __shared__ int h[NR];
    int t = threadIdx.x, b = blockIdx.x;
    for (int i = t; i < NR; i += 256) h[i] = 0;
    __syncthreads();
    for (int i = b * 256 + t; i < NE; i += NBK * 256) {
        int d = ei[NE + i];
        atomicAdd(&h[d / RSZ], 1);               // LDS atomic
    }
    __syncthreads();
    for (int i = t; i < NR; i += 256) blkhist[(size_t)b * NR + i] = h[i];
}

// ---------------- scanR1: per-range exclusive scan over blocks -------------
__global__ __launch_bounds__(512) void k_scanR1(int* __restrict__ blkhist,
                                                int* __restrict__ rtot) {
    __shared__ int sh[NBK];
    int r = blockIdx.x, t = threadIdx.x;
    int v = blkhist[(size_t)t * NR + r];
    sh[t] = v;
    __syncthreads();
    for (int off = 1; off < NBK; off <<= 1) {
        int u = (t >= off) ? sh[t - off] : 0;
        __syncthreads();
        sh[t] += u;
        __syncthreads();
    }
    blkhist[(size_t)t * NR + r] = sh[t] - v;     // block-local prefix
    if (t == NBK - 1) rtot[r] = sh[t];
}

// ---------------- scanR2: exclusive scan of range totals -------------------
__global__ __launch_bounds__(512) void k_scanR2(const int* __restrict__ rtot,
                                                int* __restrict__ rangeBase) {
    __shared__ int sh[512];
    int t = threadIdx.x;
    int v = (t < NR) ? rtot[t] : 0;
    sh[t] = v;
    __syncthreads();
    for (int off = 1; off < 512; off <<= 1) {
        int u = (t >= off) ? sh[t - off] : 0;
        __syncthreads();
        sh[t] += u;
        __syncthreads();
    }
    if (t < NR) rangeBase[t] = sh[t] - v;
    if (t == NR - 1) rangeBase[NR] = sh[t];      // == NE
}

// ---------------- P2: scatter edges into range buckets (LDS cursors) -------
__global__ __launch_bounds__(256) void k_p2(const int* __restrict__ ei,
                                            const int* __restrict__ blkhist,
                                            const int* __restrict__ rangeBase,
                                            int2* __restrict__ bucket) {
    __shared__ int cur[NR];
    int t = threadIdx.x, b = blockIdx.x;
    for (int i = t; i < NR; i += 256)
        cur[i] = rangeBase[i] + blkhist[(size_t)b * NR + i];
    __syncthreads();
    for (int i = b * 256 + t; i < NE; i += NBK * 256) {   // same slice as k_p1
        int s = ei[i];
        int d = ei[NE + i];
        int pos = atomicAdd(&cur[d / RSZ], 1);            // LDS atomic
        bucket[pos] = make_int2(s, d);
    }
}

// ---------------- P3: per-range CSR finalize (LDS count+scan+cursor) -------
__global__ __launch_bounds__(256) void k_p3(const int2* __restrict__ bucket,
                                            const int* __restrict__ rangeBase,
                                            int2* __restrict__ odpk,
                                            float* __restrict__ inv,
                                            int* __restrict__ csr_s) {
    __shared__ int cnt[RSZ];
    __shared__ int base[RSZ];
    __shared__ int sc[256];
    int r = blockIdx.x, t = threadIdx.x;
    int e0 = rangeBase[r], e1 = rangeBase[r + 1];
    int n0 = r * RSZ;
    if (t < RSZ) cnt[t] = 0;
    __syncthreads();
    for (int i = e0 + t; i < e1; i += 256)
        atomicAdd(&cnt[bucket[i].y - n0], 1);             // LDS atomic
    __syncthreads();
    int v = (t < RSZ) ? cnt[t] : 0;
    sc[t] = v;
    __syncthreads();
    for (int off = 1; off < 256; off <<= 1) {
        int u = (t >= off) ? sc[t - off] : 0;
        __syncthreads();
        sc[t] += u;
        __syncthreads();
    }
    if (t < RSZ) {
        int o = e0 + sc[t] - v;                           // global CSR offset
        odpk[n0 + t] = make_int2(o, v);
        inv[n0 + t] = rsqrtf((float)v + 1.0f);
        base[t] = o;                                      // cursor start
    }
    __syncthreads();
    for (int i = e0 + t; i < e1; i += 256) {
        int2 sd = bucket[i];
        int p = atomicAdd(&base[sd.y - n0], 1);           // LDS atomic
        csr_s[p] = sd.x;
    }
}

// ---------------- GEMM1: h0s[N,64] = (x[N,128] @ W1) * inv[row]  (fp16) ----
#define XS_STRIDE 132   // 128 + 4: keeps b128 16B-aligned; rows on distinct banks
__global__ __launch_bounds__(256) void k_gemm1(const float* __restrict__ x,
                                               const float* __restrict__ W1,
                                               const float* __restrict__ inv,
                                               f16* __restrict__ h0s) {
    __shared__ float xs[64 * XS_STRIDE];   // 33.8 KB
    __shared__ float ws[64 * FH];          // 16 KB (one K-half of W1)
    int t = threadIdx.x;
    int row0 = blockIdx.x * 64;
    {
        int r = t >> 5;              // 0..7
        int c4 = (t & 31) * 4;       // 0..124
#pragma unroll
        for (int p = 0; p < 8; ++p) {
            int row = row0 + r + p * 8;
            float4 v = make_float4(0.f, 0.f, 0.f, 0.f);
            if (row < NN) v = *(const float4*)&x[(size_t)row * FI + c4];
            *(float4*)&xs[(r + p * 8) * XS_STRIDE + c4] = v;
        }
    }
    float acc[4][4] = {{0.f}};
    int tx4 = (t & 15) * 4;
    int ty4 = (t >> 4) * 4;
#pragma unroll
    for (int half = 0; half < 2; ++half) {
        __syncthreads();
        {
            const float4* Wv = (const float4*)(W1 + half * 64 * FH);
            float4* wv = (float4*)ws;
            for (int i = t; i < 64 * FH / 4; i += 256) wv[i] = Wv[i];
        }
        __syncthreads();
#pragma unroll 2
        for (int k = 0; k < 64; k += 4) {
            float4 a0 = *(const float4*)&xs[(ty4 + 0) * XS_STRIDE + half * 64 + k];
            float4 a1 = *(const float4*)&xs[(ty4 + 1) * XS_STRIDE + half * 64 + k];
            float4 a2 = *(const float4*)&xs[(ty4 + 2) * XS_STRIDE + half * 64 + k];
            float4 a3 = *(const float4*)&xs[(ty4 + 3) * XS_STRIDE + half * 64 + k];
            float4 b0 = *(const float4*)&ws[(k + 0) * FH + tx4];
            float4 b1 = *(const float4*)&ws[(k + 1) * FH + tx4];
            float4 b2 = *(const float4*)&ws[(k + 2) * FH + tx4];
            float4 b3 = *(const float4*)&ws[(k + 3) * FH + tx4];
#define KK1(AE, BV) \
            acc[0][0] = fmaf(a0.AE, BV.x, acc[0][0]); \
            acc[0][1] = fmaf(a0.AE, BV.y, acc[0][1]); \
            acc[0][2] = fmaf(a0.AE, BV.z, acc[0][2]); \
            acc[0][3] = fmaf(a0.AE, BV.w, acc[0][3]); \
            acc[1][0] = fmaf(a1.AE, BV.x, acc[1][0]); \
            acc[1][1] = fmaf(a1.AE, BV.y, acc[1][1]); \
            acc[1][2] = fmaf(a1.AE, BV.z, acc[1][2]); \
            acc[1][3] = fmaf(a1.AE, BV.w, acc[1][3]); \
            acc[2][0] = fmaf(a2.AE, BV.x, acc[2][0]); \
            acc[2][1] = fmaf(a2.AE, BV.y, acc[2][1]); \
            acc[2][2] = fmaf(a2.AE, BV.z, acc[2][2]); \
            acc[2][3] = fmaf(a2.AE, BV.w, acc[2][3]); \
            acc[3][0] = fmaf(a3.AE, BV.x, acc[3][0]); \
            acc[3][1] = fmaf(a3.AE, BV.y, acc[3][1]); \
            acc[3][2] = fmaf(a3.AE, BV.z, acc[3][2]); \
            acc[3][3] = fmaf(a3.AE, BV.w, acc[3][3]);
            KK1(x, b0) KK1(y, b1) KK1(z, b2) KK1(w, b3)
#undef KK1
        }
    }
#pragma unroll
    for (int i = 0; i < 4; ++i) {
        int row = row0 + ty4 + i;
        if (row < NN) {
            float s = inv[row];
            union { f16 h[4]; uint2 u; } p;
            p.h[0] = (f16)(acc[i][0] * s);
            p.h[1] = (f16)(acc[i][1] * s);
            p.h[2] = (f16)(acc[i][2] * s);
            p.h[3] = (f16)(acc[i][3] * s);
            *(uint2*)&h0s[(size_t)row * FH + tx4] = p.u;
        }
    }
}

// ---------------- agg1: paired-lane gather + self + bias + relu + dropout --
// lane = (parity p = lane>>5, feature pair c2 = (lane&31)*2).
// One 4B/lane load fetches TWO edge rows; 8-edge unroll -> 8 rows in flight.
__global__ __launch_bounds__(256) void k_agg1(const int2* __restrict__ odpk,
                                              const int* __restrict__ csr_s,
                                              const float* __restrict__ inv,
                                              const f16* __restrict__ h0s,
                                              const float* __restrict__ b1,
                                              float* __restrict__ h1) {
    int lane = threadIdx.x & 63;
    int d = __builtin_amdgcn_readfirstlane((int)(blockIdx.x * 4 + (threadIdx.x >> 6)));
    if (d >= NN) return;
    int p = lane >> 5;
    int c2 = (lane & 31) * 2;
    int2 od = odpk[d];
    int start = od.x, deg = od.y;
    float a0 = 0.f, a1 = 0.f;
    int k = 0;
    for (; k + 8 <= deg; k += 8) {
        int s0 = csr_s[start + k + 0], s1 = csr_s[start + k + 1];
        int s2 = csr_s[start + k + 2], s3 = csr_s[start + k + 3];
        int s4 = csr_s[start + k + 4], s5 = csr_s[start + k + 5];
        int s6 = csr_s[start + k + 6], s7 = csr_s[start + k + 7];
        int i0 = p ? s1 : s0;
        int i1 = p ? s3 : s2;
        int i2 = p ? s5 : s4;
        int i3 = p ? s7 : s6;
        unsigned u0 = *(const unsigned*)&h0s[(size_t)i0 * FH + c2];
        unsigned u1 = *(const unsigned*)&h0s[(size_t)i1 * FH + c2];
        unsigned u2 = *(const unsigned*)&h0s[(size_t)i2 * FH + c2];
        unsigned u3 = *(const unsigned*)&h0s[(size_t)i3 * FH + c2];
        float lo, hi;
        unpack2(u0, lo, hi); a0 += lo; a1 += hi;
        unpack2(u1, lo, hi); a0 += lo; a1 += hi;
        unpack2(u2, lo, hi); a0 += lo; a1 += hi;
        unpack2(u3, lo, hi); a0 += lo; a1 += hi;
    }
    for (; k + 2 <= deg; k += 2) {
        int s0 = csr_s[start + k], s1 = csr_s[start + k + 1];
        int i0 = p ? s1 : s0;
        unsigned u0 = *(const unsigned*)&h0s[(size_t)i0 * FH + c2];
        float lo, hi;
        unpack2(u0, lo, hi); a0 += lo; a1 += hi;
    }
    if (k < deg) {
        int s = csr_s[start + k];
        if (p == 0) {
            unsigned u = *(const unsigned*)&h0s[(size_t)s * FH + c2];
            float lo, hi;
            unpack2(u, lo, hi); a0 += lo; a1 += hi;
        }
    }
    // combine parities
    a0 += __shfl_xor(a0, 32, 64);
    a1 += __shfl_xor(a1, 32, 64);
    // self term + bias + relu
    float invd = inv[d];
    unsigned su = *(const unsigned*)&h0s[(size_t)d * FH + c2];
    float slo, shi;
    unpack2(su, slo, shi);
    float2 bv = *(const float2*)&b1[c2];
    float v0 = fmaxf((a0 + slo) * invd + bv.x, 0.f);
    float v1 = fmaxf((a1 + shi) * invd + bv.y, 0.f);
    // dropout: 1 threefry per lane (feature=lane), redistribute via shfl
    unsigned o0, o1;
    threefry_0_42(0u, (unsigned)(d * FH + lane), o0, o1);
    unsigned keep = (((o0 ^ o1) >> 31) ^ 1u);   // 1 = keep
    unsigned k0 = __shfl(keep, c2, 64);
    unsigned k1 = __shfl(keep, c2 + 1, 64);
    if (lane < 32) {
        float2 st;
        st.x = k0 ? v0 * 2.f : 0.f;
        st.y = k1 ? v1 * 2.f : 0.f;
        *(float2*)&h1[(size_t)d * FH + c2] = st;
    }
}

// ---------------- GEMM2: h2s[N,64(pad)] = (h1 @ W2) * inv[row]  (fp16) -----
#define HS_STRIDE 68    // 64 + 4: b128-aligned, rows on distinct banks
__global__ __launch_bounds__(256) void k_gemm2(const float* __restrict__ h,
                                               const float* __restrict__ W2,
                                               const float* __restrict__ inv,
                                               f16* __restrict__ h2s) {
    __shared__ float hs[64 * HS_STRIDE];   // 17.4 KB
    __shared__ float ws[FH * 64];          // 16 KB, cols 40..63 zero
    int t = threadIdx.x;
    int row0 = blockIdx.x * 64;
    {
        int r = t >> 4;              // 0..15
        int c4 = (t & 15) * 4;       // 0..60
#pragma unroll
        for (int p = 0; p < 4; ++p) {
            int row = row0 + r + p * 16;
            float4 v = make_float4(0.f, 0.f, 0.f, 0.f);
            if (row < NN) v = *(const float4*)&h[(size_t)row * FH + c4];
            *(float4*)&hs[(r + p * 16) * HS_STRIDE + c4] = v;
        }
    }
    for (int i = t; i < FH * 64; i += 256) {
        int r = i >> 6, c = i & 63;
        ws[i] = (c < FO) ? W2[r * FO + c] : 0.f;
    }
    __syncthreads();
    float acc[4][4] = {{0.f}};
    int tx4 = (t & 15) * 4;
    int ty4 = (t >> 4) * 4;
#pragma unroll 2
    for (int k = 0; k < FH; k += 4) {
        float4 a0 = *(const float4*)&hs[(ty4 + 0) * HS_STRIDE + k];
        float4 a1 = *(const float4*)&hs[(ty4 + 1) * HS_STRIDE + k];
        float4 a2 = *(const float4*)&hs[(ty4 + 2) * HS_STRIDE + k];
        float4 a3 = *(const float4*)&hs[(ty4 + 3) * HS_STRIDE + k];
        float4 b0 = *(const float4*)&ws[(k + 0) * 64 + tx4];
        float4 b1 = *(const float4*)&ws[(k + 1) * 64 + tx4];
        float4 b2 = *(const float4*)&ws[(k + 2) * 64 + tx4];
        float4 b3 = *(const float4*)&ws[(k + 3) * 64 + tx4];
#define KK2(AE, BV) \
        acc[0][0] = fmaf(a0.AE, BV.x, acc[0][0]); \
        acc[0][1] = fmaf(a0.AE, BV.y, acc[0][1]); \
        acc[0][2] = fmaf(a0.AE, BV.z, acc[0][2]); \
        acc[0][3] = fmaf(a0.AE, BV.w, acc[0][3]); \
        acc[1][0] = fmaf(a1.AE, BV.x, acc[1][0]); \
        acc[1][1] = fmaf(a1.AE, BV.y, acc[1][1]); \
        acc[1][2] = fmaf(a1.AE, BV.z, acc[1][2]); \
        acc[1][3] = fmaf(a1.AE, BV.w, acc[1][3]); \
        acc[2][0] = fmaf(a2.AE, BV.x, acc[2][0]); \
        acc[2][1] = fmaf(a2.AE, BV.y, acc[2][1]); \
        acc[2][2] = fmaf(a2.AE, BV.z, acc[2][2]); \
        acc[2][3] = fmaf(a2.AE, BV.w, acc[2][3]); \
        acc[3][0] = fmaf(a3.AE, BV.x, acc[3][0]); \
        acc[3][1] = fmaf(a3.AE, BV.y, acc[3][1]); \
        acc[3][2] = fmaf(a3.AE, BV.z, acc[3][2]); \
        acc[3][3] = fmaf(a3.AE, BV.w, acc[3][3]);
        KK2(x, b0) KK2(y, b1) KK2(z, b2) KK2(w, b3)
#undef KK2
    }
#pragma unroll
    for (int i = 0; i < 4; ++i) {
        int row = row0 + ty4 + i;
        if (row < NN) {
            float s = inv[row];
            union { f16 h[4]; uint2 u; } p;
            p.h[0] = (f16)(acc[i][0] * s);
            p.h[1] = (f16)(acc[i][1] * s);
            p.h[2] = (f16)(acc[i][2] * s);
            p.h[3] = (f16)(acc[i][3] * s);
            *(uint2*)&h2s[(size_t)row * FH + tx4] = p.u;
        }
    }
}

// ---------------- agg2: paired-lane gather + self + b2 -> out --------------
__global__ __launch_bounds__(256) void k_agg2(const int2* __restrict__ odpk,
                                              const int* __restrict__ csr_s,
                                              const float* __restrict__ inv,
                                              const f16* __restrict__ h2s,
                                              const float* __restrict__ b2,
                                              float* __restrict__ out) {
    int lane = threadIdx.x & 63;
    int d = __builtin_amdgcn_readfirstlane((int)(blockIdx.x * 4 + (threadIdx.x >> 6)));
    if (d >= NN) return;
    int p = lane >> 5;
    int c2 = (lane & 31) * 2;
    int2 od = odpk[d];
    int start = od.x, deg = od.y;
    float a0 = 0.f, a1 = 0.f;
    int k = 0;
    for (; k + 8 <= deg; k += 8) {
        int s0 = csr_s[start + k + 0], s1 = csr_s[start + k + 1];
        int s2 = csr_s[start + k + 2], s3 = csr_s[start + k + 3];
        int s4 = csr_s[start + k + 4], s5 = csr_s[start + k + 5];
        int s6 = csr_s[start + k + 6], s7 = csr_s[start + k + 7];
        int i0 = p ? s1 : s0;
        int i1 = p ? s3 : s2;
        int i2 = p ? s5 : s4;
        int i3 = p ? s7 : s6;
        unsigned u0 = *(const unsigned*)&h2s[(size_t)i0 * FH + c2];
        unsigned u1 = *(const unsigned*)&h2s[(size_t)i1 * FH + c2];
        unsigned u2 = *(const unsigned*)&h2s[(size_t)i2 * FH + c2];
        unsigned u3 = *(const unsigned*)&h2s[(size_t)i3 * FH + c2];
        float lo, hi;
        unpack2(u0, lo, hi); a0 += lo; a1 += hi;
        unpack2(u1, lo, hi); a0 += lo; a1 += hi;
        unpack2(u2, lo, hi); a0 += lo; a1 += hi;
        unpack2(u3, lo, hi); a0 += lo; a1 += hi;
    }
    for (; k + 2 <= deg; k += 2) {
        int s0 = csr_s[start + k], s1 = csr_s[start + k + 1];
        int i0 = p ? s1 : s0;
        unsigned u0 = *(const unsigned*)&h2s[(size_t)i0 * FH + c2];
        float lo, hi;
        unpack2(u0, lo, hi); a0 += lo; a1 += hi;
    }
    if (k < deg) {
        int s = csr_s[start + k];
        if (p == 0) {
            unsigned u = *(const unsigned*)&h2s[(size_t)s * FH + c2];
            float lo, hi;
            unpack2(u, lo, hi); a0 += lo; a1 += hi;
        }
    }
    a0 += __shfl_xor(a0, 32, 64);
    a1 += __shfl_xor(a1, 32, 64);
    if (lane < 20) {                              // c2 <= 38 -> cols 0..39
        float invd = inv[d];
        unsigned su = *(const unsigned*)&h2s[(size_t)d * FH + c2];
        float slo, shi;
        unpack2(su, slo, shi);
        float2 bv = *(const float2*)&b2[c2];
        float2 st;
        st.x = (a0 + slo) * invd + bv.x;
        st.y = (a1 + shi) * invd + bv.y;
        *(float2*)&out[(size_t)d * FO + c2] = st;
    }
}

extern "C" void kernel_launch(void* const* d_in, const int* in_sizes, int n_in,
                              void* d_out, int out_size, void* d_ws, size_t ws_size,
                              hipStream_t stream) {
    const float* x  = (const float*)d_in[0];
    const int*   ei = (const int*)d_in[1];   // int32 [2, NE]: src = ei[e], dst = ei[NE+e]
    const float* W1 = (const float*)d_in[2];
    const float* b1 = (const float*)d_in[3];
    const float* W2 = (const float*)d_in[4];
    const float* b2 = (const float*)d_in[5];
    float* out = (float*)d_out;

    char* ws = (char*)d_ws;
    int*   blkhist   = (int*)ws;                              // 1.0 MB (512*500)
    int*   rtot      = (int*)(ws + (size_t)(1 << 20) + 102400);   // 2 KB
    int*   rangeBase = (int*)(ws + (size_t)(1 << 20) + 106496);   // 2 KB (501)
    float* inv       = (float*)(ws + (size_t)( 2 << 20));     // 0.4 MB
    int2*  odpk      = (int2*)(ws + (size_t)( 3 << 20));      // 0.8 MB
    int2*  bucket    = (int2*)(ws + (size_t)( 4 << 20));      // 12.8 MB (dead after p3)
    f16*   h2s       = (f16*)bucket;                          // 12.8 MB (reuses bucket)
    int*   csr_s     = (int*)(ws + (size_t)(17 << 20));       // 6.4 MB
    f16*   h0s       = (f16*)(ws + (size_t)(24 << 20));       // 12.8 MB
    float* h1        = (float*)(ws + (size_t)(37 << 20));     // 25.6 MB

    k_p1<<<NBK, 256, 0, stream>>>(ei, blkhist);
    k_scanR1<<<NR, 512, 0, stream>>>(blkhist, rtot);
    k_scanR2<<<1, 512, 0, stream>>>(rtot, rangeBase);
    k_p2<<<NBK, 256, 0, stream>>>(ei, blkhist, rangeBase, bucket);
    k_p3<<<NR, 256, 0, stream>>>(bucket, rangeBase, odpk, inv, csr_s);

    int gblk = (NN + 63) / 64;   // 1563
    k_gemm1<<<gblk, 256, 0, stream>>>(x, W1, inv, h0s);
    k_agg1<<<NN / 4, 256, 0, stream>>>(odpk, csr_s, inv, h0s, b1, h1);

    k_gemm2<<<gblk, 256, 0, stream>>>(h1, W2, inv, h2s);
    k_agg2<<<NN / 4, 256, 0, stream>>>(odpk, csr_s, inv, h2s, b2, out);
}

// Round 15
// 186.231 us; speedup vs baseline: 1.4101x; 1.0330x over previous
//
#include <hip/hip_runtime.h>

#define NN 100000
#define NE 1600000
#define FI 128
#define FH 64
#define FO 40
#define NR 500      // dst ranges
#define RSZ 200     // nodes per range (NR*RSZ == NN)
#define NBK 512     // histogram/scatter blocks

typedef _Float16 f16;

// ---------------- Threefry-2x32, key = (0, 42) -----------------------------
__device__ __forceinline__ unsigned rotl32(unsigned v, unsigned r) {
    return (v << r) | (v >> (32u - r));
}

__device__ __forceinline__ void threefry_0_42(unsigned x0, unsigned x1,
                                              unsigned& o0, unsigned& o1) {
    const unsigned k0 = 0u, k1 = 42u;
    const unsigned k2 = 0x1BD11BDAu ^ k0 ^ k1;
    x0 += k0; x1 += k1;
#define TFR(r) { x0 += x1; x1 = rotl32(x1, r); x1 ^= x0; }
    TFR(13) TFR(15) TFR(26) TFR(6)   x0 += k1; x1 += k2 + 1u;
    TFR(17) TFR(29) TFR(16) TFR(24)  x0 += k2; x1 += k0 + 2u;
    TFR(13) TFR(15) TFR(26) TFR(6)   x0 += k0; x1 += k1 + 3u;
    TFR(17) TFR(29) TFR(16) TFR(24)  x0 += k1; x1 += k2 + 4u;
    TFR(13) TFR(15) TFR(26) TFR(6)   x0 += k2; x1 += k0 + 5u;
#undef TFR
    o0 = x0; o1 = x1;
}

__device__ __forceinline__ void unpack2(unsigned u, float& lo, float& hi) {
    union { unsigned u; f16 h[2]; } c;
    c.u = u;
    lo = (float)c.h[0];
    hi = (float)c.h[1];
}

// select one of 4 wave-uniform values by per-lane parity p (0..3)
__device__ __forceinline__ int sel4(int p, int s0, int s1, int s2, int s3) {
    int t0 = (p & 1) ? s1 : s0;
    int t1 = (p & 1) ? s3 : s2;
    return (p & 2) ? t1 : t0;
}

// ---------------- P1: per-block LDS range histogram ------------------------
__global__ __launch_bounds__(256) void k_p1(const int* __restrict__ ei,
                                            int* __restrict__ blkhist) {
    __shared__ int h[NR];
    int t = threadIdx.x, b = blockIdx.x;
    for (int i = t; i < NR; i += 256) h[i] = 0;
    __syncthreads();
    for (int i = b * 256 + t; i < NE; i += NBK * 256) {
        int d = ei[NE + i];
        atomicAdd(&h[d / RSZ], 1);               // LDS atomic
    }
    __syncthreads();
    for (int i = t; i < NR; i += 256) blkhist[(size_t)b * NR + i] = h[i];
}

// ---------------- scanR1: per-range exclusive scan over blocks -------------
__global__ __launch_bounds__(512) void k_scanR1(int* __restrict__ blkhist,
                                                int* __restrict__ rtot) {
    __shared__ int sh[NBK];
    int r = blockIdx.x, t = threadIdx.x;
    int v = blkhist[(size_t)t * NR + r];
    sh[t] = v;
    __syncthreads();
    for (int off = 1; off < NBK; off <<= 1) {
        int u = (t >= off) ? sh[t - off] : 0;
        __syncthreads();
        sh[t] += u;
        __syncthreads();
    }
    blkhist[(size_t)t * NR + r] = sh[t] - v;     // block-local prefix
    if (t == NBK - 1) rtot[r] = sh[t];
}

// ---------------- scanR2: exclusive scan of range totals -------------------
__global__ __launch_bounds__(512) void k_scanR2(const int* __restrict__ rtot,
                                                int* __restrict__ rangeBase) {
    __shared__ int sh[512];
    int t = threadIdx.x;
    int v = (t < NR) ? rtot[t] : 0;
    sh[t] = v;
    __syncthreads();
    for (int off = 1; off < 512; off <<= 1) {
        int u = (t >= off) ? sh[t - off] : 0;
        __syncthreads();
        sh[t] += u;
        __syncthreads();
    }
    if (t < NR) rangeBase[t] = sh[t] - v;
    if (t == NR - 1) rangeBase[NR] = sh[t];      // == NE
}

// ---------------- P2: scatter edges into range buckets (LDS cursors) -------
__global__ __launch_bounds__(256) void k_p2(const int* __restrict__ ei,
                                            const int* __restrict__ blkhist,
                                            const int* __restrict__ rangeBase,
                                            int2* __restrict__ bucket) {
    __shared__ int cur[NR];
    int t = threadIdx.x, b = blockIdx.x;
    for (int i = t; i < NR; i += 256)
        cur[i] = rangeBase[i] + blkhist[(size_t)b * NR + i];
    __syncthreads();
    for (int i = b * 256 + t; i < NE; i += NBK * 256) {   // same slice as k_p1
        int s = ei[i];
        int d = ei[NE + i];
        int pos = atomicAdd(&cur[d / RSZ], 1);            // LDS atomic
        bucket[pos] = make_int2(s, d);
    }
}

// ---------------- P3: per-range CSR finalize, segments padded to x4 --------
// Padded entries point to src = NN (all-zero feature row) -> tail-free agg.
__global__ __launch_bounds__(256) void k_p3(const int2* __restrict__ bucket,
                                            const int* __restrict__ rangeBase,
                                            int2* __restrict__ odpk,
                                            float* __restrict__ inv,
                                            int* __restrict__ csr_s) {
    __shared__ int cnt[RSZ];
    __shared__ int base[RSZ];
    __shared__ int sc[256];
    int r = blockIdx.x, t = threadIdx.x;
    int e0 = rangeBase[r], e1 = rangeBase[r + 1];
    int padBase = e0 + 3 * RSZ * r;                       // padded global base
    int n0 = r * RSZ;
    if (t < RSZ) cnt[t] = 0;
    __syncthreads();
    for (int i = e0 + t; i < e1; i += 256)
        atomicAdd(&cnt[bucket[i].y - n0], 1);             // LDS atomic
    __syncthreads();
    int v = 0, vp = 0;
    if (t < RSZ) {
        v = cnt[t];
        vp = (v + 3) & ~3;                                // padded count
    }
    sc[t] = vp;
    __syncthreads();
    for (int off = 1; off < 256; off <<= 1) {
        int u = (t >= off) ? sc[t - off] : 0;
        __syncthreads();
        sc[t] += u;
        __syncthreads();
    }
    int o = 0;
    if (t < RSZ) {
        o = padBase + sc[t] - vp;                         // padded CSR offset
        odpk[n0 + t] = make_int2(o, vp);                  // loop bound = padded
        inv[n0 + t] = rsqrtf((float)v + 1.0f);            // norm from real deg
        base[t] = o;                                      // cursor start
    }
    __syncthreads();
    for (int i = e0 + t; i < e1; i += 256) {
        int2 sd = bucket[i];
        int p = atomicAdd(&base[sd.y - n0], 1);           // LDS atomic
        csr_s[p] = sd.x;
    }
    __syncthreads();
    if (t < RSZ) {
        for (int j = v; j < vp; ++j) csr_s[o + j] = NN;   // sentinel pads
    }
}

// ---------------- GEMM1: h0s[N,64] = (x @ W1) * inv[row] (fp16, +zero row) -
#define XS_STRIDE 132   // 128 + 4: keeps b128 16B-aligned; rows on distinct banks
__global__ __launch_bounds__(256) void k_gemm1(const float* __restrict__ x,
                                               const float* __restrict__ W1,
                                               const float* __restrict__ inv,
                                               f16* __restrict__ h0s) {
    __shared__ float xs[64 * XS_STRIDE];   // 33.8 KB
    __shared__ float ws[64 * FH];          // 16 KB (one K-half of W1)
    int t = threadIdx.x;
    int row0 = blockIdx.x * 64;
    {
        int r = t >> 5;              // 0..7
        int c4 = (t & 31) * 4;       // 0..124
#pragma unroll
        for (int p = 0; p < 8; ++p) {
            int row = row0 + r + p * 8;
            float4 v = make_float4(0.f, 0.f, 0.f, 0.f);
            if (row < NN) v = *(const float4*)&x[(size_t)row * FI + c4];
            *(float4*)&xs[(r + p * 8) * XS_STRIDE + c4] = v;
        }
    }
    float acc[4][4] = {{0.f}};
    int tx4 = (t & 15) * 4;
    int ty4 = (t >> 4) * 4;
#pragma unroll
    for (int half = 0; half < 2; ++half) {
        __syncthreads();
        {
            const float4* Wv = (const float4*)(W1 + half * 64 * FH);
            float4* wv = (float4*)ws;
            for (int i = t; i < 64 * FH / 4; i += 256) wv[i] = Wv[i];
        }
        __syncthreads();
#pragma unroll 2
        for (int k = 0; k < 64; k += 4) {
            float4 a0 = *(const float4*)&xs[(ty4 + 0) * XS_STRIDE + half * 64 + k];
            float4 a1 = *(const float4*)&xs[(ty4 + 1) * XS_STRIDE + half * 64 + k];
            float4 a2 = *(const float4*)&xs[(ty4 + 2) * XS_STRIDE + half * 64 + k];
            float4 a3 = *(const float4*)&xs[(ty4 + 3) * XS_STRIDE + half * 64 + k];
            float4 b0 = *(const float4*)&ws[(k + 0) * FH + tx4];
            float4 b1 = *(const float4*)&ws[(k + 1) * FH + tx4];
            float4 b2 = *(const float4*)&ws[(k + 2) * FH + tx4];
            float4 b3 = *(const float4*)&ws[(k + 3) * FH + tx4];
#define KK1(AE, BV) \
            acc[0][0] = fmaf(a0.AE, BV.x, acc[0][0]); \
            acc[0][1] = fmaf(a0.AE, BV.y, acc[0][1]); \
            acc[0][2] = fmaf(a0.AE, BV.z, acc[0][2]); \
            acc[0][3] = fmaf(a0.AE, BV.w, acc[0][3]); \
            acc[1][0] = fmaf(a1.AE, BV.x, acc[1][0]); \
            acc[1][1] = fmaf(a1.AE, BV.y, acc[1][1]); \
            acc[1][2] = fmaf(a1.AE, BV.z, acc[1][2]); \
            acc[1][3] = fmaf(a1.AE, BV.w, acc[1][3]); \
            acc[2][0] = fmaf(a2.AE, BV.x, acc[2][0]); \
            acc[2][1] = fmaf(a2.AE, BV.y, acc[2][1]); \
            acc[2][2] = fmaf(a2.AE, BV.z, acc[2][2]); \
            acc[2][3] = fmaf(a2.AE, BV.w, acc[2][3]); \
            acc[3][0] = fmaf(a3.AE, BV.x, acc[3][0]); \
            acc[3][1] = fmaf(a3.AE, BV.y, acc[3][1]); \
            acc[3][2] = fmaf(a3.AE, BV.z, acc[3][2]); \
            acc[3][3] = fmaf(a3.AE, BV.w, acc[3][3]);
            KK1(x, b0) KK1(y, b1) KK1(z, b2) KK1(w, b3)
#undef KK1
        }
    }
#pragma unroll
    for (int i = 0; i < 4; ++i) {
        int row = row0 + ty4 + i;
        if (row < NN) {
            float s = inv[row];
            union { f16 h[4]; uint2 u; } p;
            p.h[0] = (f16)(acc[i][0] * s);
            p.h[1] = (f16)(acc[i][1] * s);
            p.h[2] = (f16)(acc[i][2] * s);
            p.h[3] = (f16)(acc[i][3] * s);
            *(uint2*)&h0s[(size_t)row * FH + tx4] = p.u;
        } else if (row == NN) {
            *(uint2*)&h0s[(size_t)row * FH + tx4] = make_uint2(0u, 0u);
        }
    }
}

// ---------------- agg1: quad-parity gather + self + bias + relu + dropout --
// lane = (parity p = lane>>4, feature quad c4 = (lane&15)*4).
// One dwordx2/lane load fetches FOUR edge rows; 8-edge iter = 2 loads.
__global__ __launch_bounds__(256) void k_agg1(const int2* __restrict__ odpk,
                                              const int* __restrict__ csr_s,
                                              const float* __restrict__ inv,
                                              const f16* __restrict__ h0s,
                                              const float* __restrict__ b1,
                                              float* __restrict__ h1) {
    int lane = threadIdx.x & 63;
    int d = __builtin_amdgcn_readfirstlane((int)(blockIdx.x * 4 + (threadIdx.x >> 6)));
    if (d >= NN) return;
    int p = lane >> 4;
    int c4 = (lane & 15) * 4;
    size_t q8 = (size_t)(lane & 15) * 8;       // byte offset within row
    const char* hb = (const char*)h0s;
    int2 od = odpk[d];
    int start = od.x, degp = od.y;             // degp % 4 == 0 (padded)
    float a0 = 0.f, a1 = 0.f, a2 = 0.f, a3 = 0.f;
    int k = 0;
    for (; k + 8 <= degp; k += 8) {
        int s0 = csr_s[start + k + 0], s1 = csr_s[start + k + 1];
        int s2 = csr_s[start + k + 2], s3 = csr_s[start + k + 3];
        int s4 = csr_s[start + k + 4], s5 = csr_s[start + k + 5];
        int s6 = csr_s[start + k + 6], s7 = csr_s[start + k + 7];
        int ia = sel4(p, s0, s1, s2, s3);
        int ib = sel4(p, s4, s5, s6, s7);
        uint2 ua = *(const uint2*)(hb + ((size_t)ia << 7) + q8);
        uint2 ub = *(const uint2*)(hb + ((size_t)ib << 7) + q8);
        float f0, f1, f2, f3;
        unpack2(ua.x, f0, f1); unpack2(ua.y, f2, f3);
        a0 += f0; a1 += f1; a2 += f2; a3 += f3;
        unpack2(ub.x, f0, f1); unpack2(ub.y, f2, f3);
        a0 += f0; a1 += f1; a2 += f2; a3 += f3;
    }
    if (k < degp) {                            // exactly 4 remain
        int s0 = csr_s[start + k + 0], s1 = csr_s[start + k + 1];
        int s2 = csr_s[start + k + 2], s3 = csr_s[start + k + 3];
        int ia = sel4(p, s0, s1, s2, s3);
        uint2 ua = *(const uint2*)(hb + ((size_t)ia << 7) + q8);
        float f0, f1, f2, f3;
        unpack2(ua.x, f0, f1); unpack2(ua.y, f2, f3);
        a0 += f0; a1 += f1; a2 += f2; a3 += f3;
    }
    // combine 4 parities
    a0 += __shfl_xor(a0, 16, 64); a0 += __shfl_xor(a0, 32, 64);
    a1 += __shfl_xor(a1, 16, 64); a1 += __shfl_xor(a1, 32, 64);
    a2 += __shfl_xor(a2, 16, 64); a2 += __shfl_xor(a2, 32, 64);
    a3 += __shfl_xor(a3, 16, 64); a3 += __shfl_xor(a3, 32, 64);
    // self + bias + relu
    float invd = inv[d];
    uint2 su = *(const uint2*)(hb + ((size_t)d << 7) + q8);
    float s0, s1, s2, s3;
    unpack2(su.x, s0, s1); unpack2(su.y, s2, s3);
    float4 bv = *(const float4*)&b1[c4];
    float v0 = fmaxf((a0 + s0) * invd + bv.x, 0.f);
    float v1 = fmaxf((a1 + s1) * invd + bv.y, 0.f);
    float v2 = fmaxf((a2 + s2) * invd + bv.z, 0.f);
    float v3 = fmaxf((a3 + s3) * invd + bv.w, 0.f);
    // dropout: 1 threefry/lane (feature=lane), pack via ballot, extract 4 bits
    unsigned o0, o1;
    threefry_0_42(0u, (unsigned)(d * FH + lane), o0, o1);
    unsigned long long m = __ballot((int)(((o0 ^ o1) >> 31) ^ 1u));
    unsigned mm = (unsigned)(m >> c4) & 15u;   // keep bits for c4..c4+3
    if (lane < 16) {
        float4 st;
        st.x = (mm & 1u) ? v0 * 2.f : 0.f;
        st.y = (mm & 2u) ? v1 * 2.f : 0.f;
        st.z = (mm & 4u) ? v2 * 2.f : 0.f;
        st.w = (mm & 8u) ? v3 * 2.f : 0.f;
        *(float4*)&h1[(size_t)d * FH + c4] = st;
    }
}

// ---------------- GEMM2: h2s[N,64pad] = (h1 @ W2) * inv[row] (fp16,+zero) --
#define HS_STRIDE 68    // 64 + 4: b128-aligned, rows on distinct banks
__global__ __launch_bounds__(256) void k_gemm2(const float* __restrict__ h,
                                               const float* __restrict__ W2,
                                               const float* __restrict__ inv,
                                               f16* __restrict__ h2s) {
    __shared__ float hs[64 * HS_STRIDE];   // 17.4 KB
    __shared__ float ws[FH * 64];          // 16 KB, cols 40..63 zero
    int t = threadIdx.x;
    int row0 = blockIdx.x * 64;
    {
        int r = t >> 4;              // 0..15
        int c4 = (t & 15) * 4;       // 0..60
#pragma unroll
        for (int p = 0; p < 4; ++p) {
            int row = row0 + r + p * 16;
            float4 v = make_float4(0.f, 0.f, 0.f, 0.f);
            if (row < NN) v = *(const float4*)&h[(size_t)row * FH + c4];
            *(float4*)&hs[(r + p * 16) * HS_STRIDE + c4] = v;
        }
    }
    for (int i = t; i < FH * 64; i += 256) {
        int r = i >> 6, c = i & 63;
        ws[i] = (c < FO) ? W2[r * FO + c] : 0.f;
    }
    __syncthreads();
    float acc[4][4] = {{0.f}};
    int tx4 = (t & 15) * 4;
    int ty4 = (t >> 4) * 4;
#pragma unroll 2
    for (int k = 0; k < FH; k += 4) {
        float4 a0 = *(const float4*)&hs[(ty4 + 0) * HS_STRIDE + k];
        float4 a1 = *(const float4*)&hs[(ty4 + 1) * HS_STRIDE + k];
        float4 a2 = *(const float4*)&hs[(ty4 + 2) * HS_STRIDE + k];
        float4 a3 = *(const float4*)&hs[(ty4 + 3) * HS_STRIDE + k];
        float4 b0 = *(const float4*)&ws[(k + 0) * 64 + tx4];
        float4 b1 = *(const float4*)&ws[(k + 1) * 64 + tx4];
        float4 b2 = *(const float4*)&ws[(k + 2) * 64 + tx4];
        float4 b3 = *(const float4*)&ws[(k + 3) * 64 + tx4];
#define KK2(AE, BV) \
        acc[0][0] = fmaf(a0.AE, BV.x, acc[0][0]); \
        acc[0][1] = fmaf(a0.AE, BV.y, acc[0][1]); \
        acc[0][2] = fmaf(a0.AE, BV.z, acc[0][2]); \
        acc[0][3] = fmaf(a0.AE, BV.w, acc[0][3]); \
        acc[1][0] = fmaf(a1.AE, BV.x, acc[1][0]); \
        acc[1][1] = fmaf(a1.AE, BV.y, acc[1][1]); \
        acc[1][2] = fmaf(a1.AE, BV.z, acc[1][2]); \
        acc[1][3] = fmaf(a1.AE, BV.w, acc[1][3]); \
        acc[2][0] = fmaf(a2.AE, BV.x, acc[2][0]); \
        acc[2][1] = fmaf(a2.AE, BV.y, acc[2][1]); \
        acc[2][2] = fmaf(a2.AE, BV.z, acc[2][2]); \
        acc[2][3] = fmaf(a2.AE, BV.w, acc[2][3]); \
        acc[3][0] = fmaf(a3.AE, BV.x, acc[3][0]); \
        acc[3][1] = fmaf(a3.AE, BV.y, acc[3][1]); \
        acc[3][2] = fmaf(a3.AE, BV.z, acc[3][2]); \
        acc[3][3] = fmaf(a3.AE, BV.w, acc[3][3]);
        KK2(x, b0) KK2(y, b1) KK2(z, b2) KK2(w, b3)
#undef KK2
    }
#pragma unroll
    for (int i = 0; i < 4; ++i) {
        int row = row0 + ty4 + i;
        if (row < NN) {
            float s = inv[row];
            union { f16 h[4]; uint2 u; } p;
            p.h[0] = (f16)(acc[i][0] * s);
            p.h[1] = (f16)(acc[i][1] * s);
            p.h[2] = (f16)(acc[i][2] * s);
            p.h[3] = (f16)(acc[i][3] * s);
            *(uint2*)&h2s[(size_t)row * FH + tx4] = p.u;
        } else if (row == NN) {
            *(uint2*)&h2s[(size_t)row * FH + tx4] = make_uint2(0u, 0u);
        }
    }
}

// ---------------- agg2: quad-parity gather + self + b2 -> out --------------
__global__ __launch_bounds__(256) void k_agg2(const int2* __restrict__ odpk,
                                              const int* __restrict__ csr_s,
                                              const float* __restrict__ inv,
                                              const f16* __restrict__ h2s,
                                              const float* __restrict__ b2,
                                              float* __restrict__ out) {
    int lane = threadIdx.x & 63;
    int d = __builtin_amdgcn_readfirstlane((int)(blockIdx.x * 4 + (threadIdx.x >> 6)));
    if (d >= NN) return;
    int p = lane >> 4;
    int c4 = (lane & 15) * 4;
    size_t q8 = (size_t)(lane & 15) * 8;
    const char* hb = (const char*)h2s;
    int2 od = odpk[d];
    int start = od.x, degp = od.y;
    float a0 = 0.f, a1 = 0.f, a2 = 0.f, a3 = 0.f;
    int k = 0;
    for (; k + 8 <= degp; k += 8) {
        int s0 = csr_s[start + k + 0], s1 = csr_s[start + k + 1];
        int s2 = csr_s[start + k + 2], s3 = csr_s[start + k + 3];
        int s4 = csr_s[start + k + 4], s5 = csr_s[start + k + 5];
        int s6 = csr_s[start + k + 6], s7 = csr_s[start + k + 7];
        int ia = sel4(p, s0, s1, s2, s3);
        int ib = sel4(p, s4, s5, s6, s7);
        uint2 ua = *(const uint2*)(hb + ((size_t)ia << 7) + q8);
        uint2 ub = *(const uint2*)(hb + ((size_t)ib << 7) + q8);
        float f0, f1, f2, f3;
        unpack2(ua.x, f0, f1); unpack2(ua.y, f2, f3);
        a0 += f0; a1 += f1; a2 += f2; a3 += f3;
        unpack2(ub.x, f0, f1); unpack2(ub.y, f2, f3);
        a0 += f0; a1 += f1; a2 += f2; a3 += f3;
    }
    if (k < degp) {
        int s0 = csr_s[start + k + 0], s1 = csr_s[start + k + 1];
        int s2 = csr_s[start + k + 2], s3 = csr_s[start + k + 3];
        int ia = sel4(p, s0, s1, s2, s3);
        uint2 ua = *(const uint2*)(hb + ((size_t)ia << 7) + q8);
        float f0, f1, f2, f3;
        unpack2(ua.x, f0, f1); unpack2(ua.y, f2, f3);
        a0 += f0; a1 += f1; a2 += f2; a3 += f3;
    }
    a0 += __shfl_xor(a0, 16, 64); a0 += __shfl_xor(a0, 32, 64);
    a1 += __shfl_xor(a1, 16, 64); a1 += __shfl_xor(a1, 32, 64);
    a2 += __shfl_xor(a2, 16, 64); a2 += __shfl_xor(a2, 32, 64);
    a3 += __shfl_xor(a3, 16, 64); a3 += __shfl_xor(a3, 32, 64);
    if (lane < 10) {                           // c4 <= 36 -> cols 0..39
        float invd = inv[d];
        uint2 su = *(const uint2*)(hb + ((size_t)d << 7) + q8);
        float s0, s1, s2, s3;
        unpack2(su.x, s0, s1); unpack2(su.y, s2, s3);
        float4 bv = *(const float4*)&b2[c4];
        float4 st;
        st.x = (a0 + s0) * invd + bv.x;
        st.y = (a1 + s1) * invd + bv.y;
        st.z = (a2 + s2) * invd + bv.z;
        st.w = (a3 + s3) * invd + bv.w;
        *(float4*)&out[(size_t)d * FO + c4] = st;
    }
}

extern "C" void kernel_launch(void* const* d_in, const int* in_sizes, int n_in,
                              void* d_out, int out_size, void* d_ws, size_t ws_size,
                              hipStream_t stream) {
    const float* x  = (const float*)d_in[0];
    const int*   ei = (const int*)d_in[1];   // int32 [2, NE]: src = ei[e], dst = ei[NE+e]
    const float* W1 = (const float*)d_in[2];
    const float* b1 = (const float*)d_in[3];
    const float* W2 = (const float*)d_in[4];
    const float* b2 = (const float*)d_in[5];
    float* out = (float*)d_out;

    char* ws = (char*)d_ws;
    int*   blkhist   = (int*)ws;                              // 1.0 MB (512*500)
    int*   rtot      = (int*)(ws + (size_t)(1 << 20) + 102400);   // 2 KB
    int*   rangeBase = (int*)(ws + (size_t)(1 << 20) + 106496);   // 2 KB (501)
    float* inv       = (float*)(ws + (size_t)( 2 << 20));     // 0.4 MB
    int2*  odpk      = (int2*)(ws + (size_t)( 3 << 20));      // 0.8 MB
    int2*  bucket    = (int2*)(ws + (size_t)( 4 << 20));      // 12.8 MB (dead after p3)
    f16*   h2s       = (f16*)bucket;                          // 12.8 MB (reuses bucket)
    int*   csr_s     = (int*)(ws + (size_t)(17 << 20));       // <=7.6 MB (padded)
    f16*   h0s       = (f16*)(ws + (size_t)(25 << 20));       // 12.8 MB (+row NN)
    float* h1        = (float*)(ws + (size_t)(38 << 20));     // 25.6 MB

    k_p1<<<NBK, 256, 0, stream>>>(ei, blkhist);
    k_scanR1<<<NR, 512, 0, stream>>>(blkhist, rtot);
    k_scanR2<<<1, 512, 0, stream>>>(rtot, rangeBase);
    k_p2<<<NBK, 256, 0, stream>>>(ei, blkhist, rangeBase, bucket);
    k_p3<<<NR, 256, 0, stream>>>(bucket, rangeBase, odpk, inv, csr_s);

    int gblk = (NN + 63) / 64;   // 1563 (covers zero row NN at row0=99968..100031)
    k_gemm1<<<gblk, 256, 0, stream>>>(x, W1, inv, h0s);
    k_agg1<<<NN / 4, 256, 0, stream>>>(odpk, csr_s, inv, h0s, b1, h1);

    k_gemm2<<<gblk, 256, 0, stream>>>(h1, W2, inv, h2s);
    k_agg2<<<NN / 4, 256, 0, stream>>>(odpk, csr_s, inv, h2s, b2, out);
}

// Round 16
// 185.774 us; speedup vs baseline: 1.4135x; 1.0025x over previous
//
#include <hip/hip_runtime.h>

#define NN 100000
#define NE 1600000
#define FI 128
#define FH 64
#define FO 40
#define NR 500      // dst ranges
#define RSZ 200     // nodes per range (NR*RSZ == NN)
#define NBK 512     // histogram/scatter blocks

typedef _Float16 f16;
typedef _Float16 f16x2 __attribute__((ext_vector_type(2)));

// ---------------- Threefry-2x32, key = (0, 42) -----------------------------
__device__ __forceinline__ unsigned rotl32(unsigned v, unsigned r) {
    return (v << r) | (v >> (32u - r));
}

__device__ __forceinline__ void threefry_0_42(unsigned x0, unsigned x1,
                                              unsigned& o0, unsigned& o1) {
    const unsigned k0 = 0u, k1 = 42u;
    const unsigned k2 = 0x1BD11BDAu ^ k0 ^ k1;
    x0 += k0; x1 += k1;
#define TFR(r) { x0 += x1; x1 = rotl32(x1, r); x1 ^= x0; }
    TFR(13) TFR(15) TFR(26) TFR(6)   x0 += k1; x1 += k2 + 1u;
    TFR(17) TFR(29) TFR(16) TFR(24)  x0 += k2; x1 += k0 + 2u;
    TFR(13) TFR(15) TFR(26) TFR(6)   x0 += k0; x1 += k1 + 3u;
    TFR(17) TFR(29) TFR(16) TFR(24)  x0 += k1; x1 += k2 + 4u;
    TFR(13) TFR(15) TFR(26) TFR(6)   x0 += k2; x1 += k0 + 5u;
#undef TFR
    o0 = x0; o1 = x1;
}

__device__ __forceinline__ void unpack2(unsigned u, float& lo, float& hi) {
    union { unsigned u; f16 h[2]; } c;
    c.u = u;
    lo = (float)c.h[0];
    hi = (float)c.h[1];
}

// select one of 4 wave-uniform values by per-lane parity p (0..3)
__device__ __forceinline__ int sel4(int p, int s0, int s1, int s2, int s3) {
    int t0 = (p & 1) ? s1 : s0;
    int t1 = (p & 1) ? s3 : s2;
    return (p & 2) ? t1 : t0;
}

// ---------------- P1: per-block LDS range histogram ------------------------
__global__ __launch_bounds__(256) void k_p1(const int* __restrict__ ei,
                                            int* __restrict__ blkhist) {
    __shared__ int h[NR];
    int t = threadIdx.x, b = blockIdx.x;
    for (int i = t; i < NR; i += 256) h[i] = 0;
    __syncthreads();
    for (int i = b * 256 + t; i < NE; i += NBK * 256) {
        int d = ei[NE + i];
        atomicAdd(&h[d / RSZ], 1);               // LDS atomic
    }
    __syncthreads();
    for (int i = t; i < NR; i += 256) blkhist[(size_t)b * NR + i] = h[i];
}

// ---------------- scanR1: per-range exclusive scan over blocks -------------
__global__ __launch_bounds__(512) void k_scanR1(int* __restrict__ blkhist,
                                                int* __restrict__ rtot) {
    __shared__ int sh[NBK];
    int r = blockIdx.x, t = threadIdx.x;
    int v = blkhist[(size_t)t * NR + r];
    sh[t] = v;
    __syncthreads();
    for (int off = 1; off < NBK; off <<= 1) {
        int u = (t >= off) ? sh[t - off] : 0;
        __syncthreads();
        sh[t] += u;
        __syncthreads();
    }
    blkhist[(size_t)t * NR + r] = sh[t] - v;     // block-local prefix
    if (t == NBK - 1) rtot[r] = sh[t];
}

// ---------------- scanR2: exclusive scan of range totals -------------------
__global__ __launch_bounds__(512) void k_scanR2(const int* __restrict__ rtot,
                                                int* __restrict__ rangeBase) {
    __shared__ int sh[512];
    int t = threadIdx.x;
    int v = (t < NR) ? rtot[t] : 0;
    sh[t] = v;
    __syncthreads();
    for (int off = 1; off < 512; off <<= 1) {
        int u = (t >= off) ? sh[t - off] : 0;
        __syncthreads();
        sh[t] += u;
        __syncthreads();
    }
    if (t < NR) rangeBase[t] = sh[t] - v;
    if (t == NR - 1) rangeBase[NR] = sh[t];      // == NE
}

// ---------------- P2: scatter edges into range buckets (LDS cursors) -------
__global__ __launch_bounds__(256) void k_p2(const int* __restrict__ ei,
                                            const int* __restrict__ blkhist,
                                            const int* __restrict__ rangeBase,
                                            int2* __restrict__ bucket) {
    __shared__ int cur[NR];
    int t = threadIdx.x, b = blockIdx.x;
    for (int i = t; i < NR; i += 256)
        cur[i] = rangeBase[i] + blkhist[(size_t)b * NR + i];
    __syncthreads();
    for (int i = b * 256 + t; i < NE; i += NBK * 256) {   // same slice as k_p1
        int s = ei[i];
        int d = ei[NE + i];
        int pos = atomicAdd(&cur[d / RSZ], 1);            // LDS atomic
        bucket[pos] = make_int2(s, d);
    }
}

// ---------------- P3: per-range CSR finalize, segments padded to x4 --------
// Padded entries point to src = NN (all-zero feature row) -> tail-free agg.
__global__ __launch_bounds__(256) void k_p3(const int2* __restrict__ bucket,
                                            const int* __restrict__ rangeBase,
                                            int2* __restrict__ odpk,
                                            float* __restrict__ inv,
                                            int* __restrict__ csr_s) {
    __shared__ int cnt[RSZ];
    __shared__ int base[RSZ];
    __shared__ int sc[256];
    int r = blockIdx.x, t = threadIdx.x;
    int e0 = rangeBase[r], e1 = rangeBase[r + 1];
    int padBase = e0 + 3 * RSZ * r;                       // padded global base
    int n0 = r * RSZ;
    if (t < RSZ) cnt[t] = 0;
    __syncthreads();
    for (int i = e0 + t; i < e1; i += 256)
        atomicAdd(&cnt[bucket[i].y - n0], 1);             // LDS atomic
    __syncthreads();
    int v = 0, vp = 0;
    if (t < RSZ) {
        v = cnt[t];
        vp = (v + 3) & ~3;                                // padded count
    }
    sc[t] = vp;
    __syncthreads();
    for (int off = 1; off < 256; off <<= 1) {
        int u = (t >= off) ? sc[t - off] : 0;
        __syncthreads();
        sc[t] += u;
        __syncthreads();
    }
    int o = 0;
    if (t < RSZ) {
        o = padBase + sc[t] - vp;                         // padded CSR offset
        odpk[n0 + t] = make_int2(o, vp);                  // loop bound = padded
        inv[n0 + t] = rsqrtf((float)v + 1.0f);            // norm from real deg
        base[t] = o;                                      // cursor start
    }
    __syncthreads();
    for (int i = e0 + t; i < e1; i += 256) {
        int2 sd = bucket[i];
        int p = atomicAdd(&base[sd.y - n0], 1);           // LDS atomic
        csr_s[p] = sd.x;
    }
    __syncthreads();
    if (t < RSZ) {
        for (int j = v; j < vp; ++j) csr_s[o + j] = NN;   // sentinel pads
    }
}

// ---------------- GEMM1: h0s[N,64] = (x @ W1) * inv[row] (fp16, +zero row) -
#define XS_STRIDE 132   // 128 + 4: keeps b128 16B-aligned; rows on distinct banks
__global__ __launch_bounds__(256) void k_gemm1(const float* __restrict__ x,
                                               const float* __restrict__ W1,
                                               const float* __restrict__ inv,
                                               f16* __restrict__ h0s) {
    __shared__ float xs[64 * XS_STRIDE];   // 33.8 KB
    __shared__ float ws[64 * FH];          // 16 KB (one K-half of W1)
    int t = threadIdx.x;
    int row0 = blockIdx.x * 64;
    {
        int r = t >> 5;              // 0..7
        int c4 = (t & 31) * 4;       // 0..124
#pragma unroll
        for (int p = 0; p < 8; ++p) {
            int row = row0 + r + p * 8;
            float4 v = make_float4(0.f, 0.f, 0.f, 0.f);
            if (row < NN) v = *(const float4*)&x[(size_t)row * FI + c4];
            *(float4*)&xs[(r + p * 8) * XS_STRIDE + c4] = v;
        }
    }
    float acc[4][4] = {{0.f}};
    int tx4 = (t & 15) * 4;
    int ty4 = (t >> 4) * 4;
#pragma unroll
    for (int half = 0; half < 2; ++half) {
        __syncthreads();
        {
            const float4* Wv = (const float4*)(W1 + half * 64 * FH);
            float4* wv = (float4*)ws;
            for (int i = t; i < 64 * FH / 4; i += 256) wv[i] = Wv[i];
        }
        __syncthreads();
#pragma unroll 2
        for (int k = 0; k < 64; k += 4) {
            float4 a0 = *(const float4*)&xs[(ty4 + 0) * XS_STRIDE + half * 64 + k];
            float4 a1 = *(const float4*)&xs[(ty4 + 1) * XS_STRIDE + half * 64 + k];
            float4 a2 = *(const float4*)&xs[(ty4 + 2) * XS_STRIDE + half * 64 + k];
            float4 a3 = *(const float4*)&xs[(ty4 + 3) * XS_STRIDE + half * 64 + k];
            float4 b0 = *(const float4*)&ws[(k + 0) * FH + tx4];
            float4 b1 = *(const float4*)&ws[(k + 1) * FH + tx4];
            float4 b2 = *(const float4*)&ws[(k + 2) * FH + tx4];
            float4 b3 = *(const float4*)&ws[(k + 3) * FH + tx4];
#define KK1(AE, BV) \
            acc[0][0] = fmaf(a0.AE, BV.x, acc[0][0]); \
            acc[0][1] = fmaf(a0.AE, BV.y, acc[0][1]); \
            acc[0][2] = fmaf(a0.AE, BV.z, acc[0][2]); \
            acc[0][3] = fmaf(a0.AE, BV.w, acc[0][3]); \
            acc[1][0] = fmaf(a1.AE, BV.x, acc[1][0]); \
            acc[1][1] = fmaf(a1.AE, BV.y, acc[1][1]); \
            acc[1][2] = fmaf(a1.AE, BV.z, acc[1][2]); \
            acc[1][3] = fmaf(a1.AE, BV.w, acc[1][3]); \
            acc[2][0] = fmaf(a2.AE, BV.x, acc[2][0]); \
            acc[2][1] = fmaf(a2.AE, BV.y, acc[2][1]); \
            acc[2][2] = fmaf(a2.AE, BV.z, acc[2][2]); \
            acc[2][3] = fmaf(a2.AE, BV.w, acc[2][3]); \
            acc[3][0] = fmaf(a3.AE, BV.x, acc[3][0]); \
            acc[3][1] = fmaf(a3.AE, BV.y, acc[3][1]); \
            acc[3][2] = fmaf(a3.AE, BV.z, acc[3][2]); \
            acc[3][3] = fmaf(a3.AE, BV.w, acc[3][3]);
            KK1(x, b0) KK1(y, b1) KK1(z, b2) KK1(w, b3)
#undef KK1
        }
    }
#pragma unroll
    for (int i = 0; i < 4; ++i) {
        int row = row0 + ty4 + i;
        if (row < NN) {
            float s = inv[row];
            union { f16 h[4]; uint2 u; } p;
            p.h[0] = (f16)(acc[i][0] * s);
            p.h[1] = (f16)(acc[i][1] * s);
            p.h[2] = (f16)(acc[i][2] * s);
            p.h[3] = (f16)(acc[i][3] * s);
            *(uint2*)&h0s[(size_t)row * FH + tx4] = p.u;
        } else if (row == NN) {
            *(uint2*)&h0s[(size_t)row * FH + tx4] = make_uint2(0u, 0u);
        }
    }
}

// ---------------- agg1: quad-parity gather (pk_add_f16) + epilogue ---------
// lane = (parity p = lane>>4, feature quad c4 = (lane&15)*4).
// Two gathered rows pre-summed in f16x2 (2 pk_add), one f32 widen per iter.
__global__ __launch_bounds__(256) void k_agg1(const int2* __restrict__ odpk,
                                              const int* __restrict__ csr_s,
                                              const float* __restrict__ inv,
                                              const f16* __restrict__ h0s,
                                              const float* __restrict__ b1,
                                              f16* __restrict__ h1s) {
    int lane = threadIdx.x & 63;
    int d = __builtin_amdgcn_readfirstlane((int)(blockIdx.x * 4 + (threadIdx.x >> 6)));
    if (d >= NN) return;
    int p = lane >> 4;
    int c4 = (lane & 15) * 4;
    size_t q8 = (size_t)(lane & 15) * 8;       // byte offset within row
    const char* hb = (const char*)h0s;
    int2 od = odpk[d];
    int start = od.x, degp = od.y;             // degp % 4 == 0 (padded)
    float a0 = 0.f, a1 = 0.f, a2 = 0.f, a3 = 0.f;
    int k = 0;
    for (; k + 8 <= degp; k += 8) {
        int s0 = csr_s[start + k + 0], s1 = csr_s[start + k + 1];
        int s2 = csr_s[start + k + 2], s3 = csr_s[start + k + 3];
        int s4 = csr_s[start + k + 4], s5 = csr_s[start + k + 5];
        int s6 = csr_s[start + k + 6], s7 = csr_s[start + k + 7];
        int ia = sel4(p, s0, s1, s2, s3);
        int ib = sel4(p, s4, s5, s6, s7);
        union { uint2 u; f16x2 h[2]; } A, B;
        A.u = *(const uint2*)(hb + ((size_t)ia << 7) + q8);
        B.u = *(const uint2*)(hb + ((size_t)ib << 7) + q8);
        f16x2 p0 = A.h[0] + B.h[0];            // v_pk_add_f16
        f16x2 p1 = A.h[1] + B.h[1];
        a0 += (float)p0[0]; a1 += (float)p0[1];
        a2 += (float)p1[0]; a3 += (float)p1[1];
    }
    if (k < degp) {                            // exactly 4 remain
        int s0 = csr_s[start + k + 0], s1 = csr_s[start + k + 1];
        int s2 = csr_s[start + k + 2], s3 = csr_s[start + k + 3];
        int ia = sel4(p, s0, s1, s2, s3);
        uint2 ua = *(const uint2*)(hb + ((size_t)ia << 7) + q8);
        float f0, f1, f2, f3;
        unpack2(ua.x, f0, f1); unpack2(ua.y, f2, f3);
        a0 += f0; a1 += f1; a2 += f2; a3 += f3;
    }
    // combine 4 parities
    a0 += __shfl_xor(a0, 16, 64); a0 += __shfl_xor(a0, 32, 64);
    a1 += __shfl_xor(a1, 16, 64); a1 += __shfl_xor(a1, 32, 64);
    a2 += __shfl_xor(a2, 16, 64); a2 += __shfl_xor(a2, 32, 64);
    a3 += __shfl_xor(a3, 16, 64); a3 += __shfl_xor(a3, 32, 64);
    // self + bias + relu
    float invd = inv[d];
    uint2 su = *(const uint2*)(hb + ((size_t)d << 7) + q8);
    float s0, s1, s2, s3;
    unpack2(su.x, s0, s1); unpack2(su.y, s2, s3);
    float4 bv = *(const float4*)&b1[c4];
    float v0 = fmaxf((a0 + s0) * invd + bv.x, 0.f);
    float v1 = fmaxf((a1 + s1) * invd + bv.y, 0.f);
    float v2 = fmaxf((a2 + s2) * invd + bv.z, 0.f);
    float v3 = fmaxf((a3 + s3) * invd + bv.w, 0.f);
    // dropout: 1 threefry/lane (feature=lane), pack via ballot, extract 4 bits
    unsigned o0, o1;
    threefry_0_42(0u, (unsigned)(d * FH + lane), o0, o1);
    unsigned long long m = __ballot((int)(((o0 ^ o1) >> 31) ^ 1u));
    unsigned mm = (unsigned)(m >> c4) & 15u;   // keep bits for c4..c4+3
    if (lane < 16) {
        union { f16 h[4]; uint2 u; } st;
        st.h[0] = (f16)((mm & 1u) ? v0 * 2.f : 0.f);
        st.h[1] = (f16)((mm & 2u) ? v1 * 2.f : 0.f);
        st.h[2] = (f16)((mm & 4u) ? v2 * 2.f : 0.f);
        st.h[3] = (f16)((mm & 8u) ? v3 * 2.f : 0.f);
        *(uint2*)&h1s[(size_t)d * FH + c4] = st.u;
    }
}

// ---------------- GEMM2: h2s[N,64pad] = (h1s @ W2) * inv[row] (f16 in/out) -
#define HS_STRIDE 68    // 64 + 4: b128-aligned, rows on distinct banks
__global__ __launch_bounds__(256) void k_gemm2(const f16* __restrict__ h1s,
                                               const float* __restrict__ W2,
                                               const float* __restrict__ inv,
                                               f16* __restrict__ h2s) {
    __shared__ float hs[64 * HS_STRIDE];   // 17.4 KB
    __shared__ float ws[FH * 64];          // 16 KB, cols 40..63 zero
    int t = threadIdx.x;
    int row0 = blockIdx.x * 64;
    {
        int r = t >> 4;              // 0..15
        int c4 = (t & 15) * 4;       // 0..60
#pragma unroll
        for (int p = 0; p < 4; ++p) {
            int row = row0 + r + p * 16;
            float4 v = make_float4(0.f, 0.f, 0.f, 0.f);
            if (row < NN) {
                uint2 u = *(const uint2*)&h1s[(size_t)row * FH + c4];
                unpack2(u.x, v.x, v.y);
                unpack2(u.y, v.z, v.w);
            }
            *(float4*)&hs[(r + p * 16) * HS_STRIDE + c4] = v;
        }
    }
    for (int i = t; i < FH * 64; i += 256) {
        int r = i >> 6, c = i & 63;
        ws[i] = (c < FO) ? W2[r * FO + c] : 0.f;
    }
    __syncthreads();
    float acc[4][4] = {{0.f}};
    int tx4 = (t & 15) * 4;
    int ty4 = (t >> 4) * 4;
#pragma unroll 2
    for (int k = 0; k < FH; k += 4) {
        float4 a0 = *(const float4*)&hs[(ty4 + 0) * HS_STRIDE + k];
        float4 a1 = *(const float4*)&hs[(ty4 + 1) * HS_STRIDE + k];
        float4 a2 = *(const float4*)&hs[(ty4 + 2) * HS_STRIDE + k];
        float4 a3 = *(const float4*)&hs[(ty4 + 3) * HS_STRIDE + k];
        float4 b0 = *(const float4*)&ws[(k + 0) * 64 + tx4];
        float4 b1 = *(const float4*)&ws[(k + 1) * 64 + tx4];
        float4 b2 = *(const float4*)&ws[(k + 2) * 64 + tx4];
        float4 b3 = *(const float4*)&ws[(k + 3) * 64 + tx4];
#define KK2(AE, BV) \
        acc[0][0] = fmaf(a0.AE, BV.x, acc[0][0]); \
        acc[0][1] = fmaf(a0.AE, BV.y, acc[0][1]); \
        acc[0][2] = fmaf(a0.AE, BV.z, acc[0][2]); \
        acc[0][3] = fmaf(a0.AE, BV.w, acc[0][3]); \
        acc[1][0] = fmaf(a1.AE, BV.x, acc[1][0]); \
        acc[1][1] = fmaf(a1.AE, BV.y, acc[1][1]); \
        acc[1][2] = fmaf(a1.AE, BV.z, acc[1][2]); \
        acc[1][3] = fmaf(a1.AE, BV.w, acc[1][3]); \
        acc[2][0] = fmaf(a2.AE, BV.x, acc[2][0]); \
        acc[2][1] = fmaf(a2.AE, BV.y, acc[2][1]); \
        acc[2][2] = fmaf(a2.AE, BV.z, acc[2][2]); \
        acc[2][3] = fmaf(a2.AE, BV.w, acc[2][3]); \
        acc[3][0] = fmaf(a3.AE, BV.x, acc[3][0]); \
        acc[3][1] = fmaf(a3.AE, BV.y, acc[3][1]); \
        acc[3][2] = fmaf(a3.AE, BV.z, acc[3][2]); \
        acc[3][3] = fmaf(a3.AE, BV.w, acc[3][3]);
        KK2(x, b0) KK2(y, b1) KK2(z, b2) KK2(w, b3)
#undef KK2
    }
#pragma unroll
    for (int i = 0; i < 4; ++i) {
        int row = row0 + ty4 + i;
        if (row < NN) {
            float s = inv[row];
            union { f16 h[4]; uint2 u; } p;
            p.h[0] = (f16)(acc[i][0] * s);
            p.h[1] = (f16)(acc[i][1] * s);
            p.h[2] = (f16)(acc[i][2] * s);
            p.h[3] = (f16)(acc[i][3] * s);
            *(uint2*)&h2s[(size_t)row * FH + tx4] = p.u;
        } else if (row == NN) {
            *(uint2*)&h2s[(size_t)row * FH + tx4] = make_uint2(0u, 0u);
        }
    }
}

// ---------------- agg2: quad-parity gather (pk_add_f16) + self + b2 --------
__global__ __launch_bounds__(256) void k_agg2(const int2* __restrict__ odpk,
                                              const int* __restrict__ csr_s,
                                              const float* __restrict__ inv,
                                              const f16* __restrict__ h2s,
                                              const float* __restrict__ b2,
                                              float* __restrict__ out) {
    int lane = threadIdx.x & 63;
    int d = __builtin_amdgcn_readfirstlane((int)(blockIdx.x * 4 + (threadIdx.x >> 6)));
    if (d >= NN) return;
    int p = lane >> 4;
    int c4 = (lane & 15) * 4;
    size_t q8 = (size_t)(lane & 15) * 8;
    const char* hb = (const char*)h2s;
    int2 od = odpk[d];
    int start = od.x, degp = od.y;
    float a0 = 0.f, a1 = 0.f, a2 = 0.f, a3 = 0.f;
    int k = 0;
    for (; k + 8 <= degp; k += 8) {
        int s0 = csr_s[start + k + 0], s1 = csr_s[start + k + 1];
        int s2 = csr_s[start + k + 2], s3 = csr_s[start + k + 3];
        int s4 = csr_s[start + k + 4], s5 = csr_s[start + k + 5];
        int s6 = csr_s[start + k + 6], s7 = csr_s[start + k + 7];
        int ia = sel4(p, s0, s1, s2, s3);
        int ib = sel4(p, s4, s5, s6, s7);
        union { uint2 u; f16x2 h[2]; } A, B;
        A.u = *(const uint2*)(hb + ((size_t)ia << 7) + q8);
        B.u = *(const uint2*)(hb + ((size_t)ib << 7) + q8);
        f16x2 p0 = A.h[0] + B.h[0];            // v_pk_add_f16
        f16x2 p1 = A.h[1] + B.h[1];
        a0 += (float)p0[0]; a1 += (float)p0[1];
        a2 += (float)p1[0]; a3 += (float)p1[1];
    }
    if (k < degp) {
        int s0 = csr_s[start + k + 0], s1 = csr_s[start + k + 1];
        int s2 = csr_s[start + k + 2], s3 = csr_s[start + k + 3];
        int ia = sel4(p, s0, s1, s2, s3);
        uint2 ua = *(const uint2*)(hb + ((size_t)ia << 7) + q8);
        float f0, f1, f2, f3;
        unpack2(ua.x, f0, f1); unpack2(ua.y, f2, f3);
        a0 += f0; a1 += f1; a2 += f2; a3 += f3;
    }
    a0 += __shfl_xor(a0, 16, 64); a0 += __shfl_xor(a0, 32, 64);
    a1 += __shfl_xor(a1, 16, 64); a1 += __shfl_xor(a1, 32, 64);
    a2 += __shfl_xor(a2, 16, 64); a2 += __shfl_xor(a2, 32, 64);
    a3 += __shfl_xor(a3, 16, 64); a3 += __shfl_xor(a3, 32, 64);
    if (lane < 10) {                           // c4 <= 36 -> cols 0..39
        float invd = inv[d];
        uint2 su = *(const uint2*)(hb + ((size_t)d << 7) + q8);
        float s0, s1, s2, s3;
        unpack2(su.x, s0, s1); unpack2(su.y, s2, s3);
        float4 bv = *(const float4*)&b2[c4];
        float4 st;
        st.x = (a0 + s0) * invd + bv.x;
        st.y = (a1 + s1) * invd + bv.y;
        st.z = (a2 + s2) * invd + bv.z;
        st.w = (a3 + s3) * invd + bv.w;
        *(float4*)&out[(size_t)d * FO + c4] = st;
    }
}

extern "C" void kernel_launch(void* const* d_in, const int* in_sizes, int n_in,
                              void* d_out, int out_size, void* d_ws, size_t ws_size,
                              hipStream_t stream) {
    const float* x  = (const float*)d_in[0];
    const int*   ei = (const int*)d_in[1];   // int32 [2, NE]: src = ei[e], dst = ei[NE+e]
    const float* W1 = (const float*)d_in[2];
    const float* b1 = (const float*)d_in[3];
    const float* W2 = (const float*)d_in[4];
    const float* b2 = (const float*)d_in[5];
    float* out = (float*)d_out;

    char* ws = (char*)d_ws;
    int*   blkhist   = (int*)ws;                              // 1.0 MB (512*500)
    int*   rtot      = (int*)(ws + (size_t)(1 << 20) + 102400);   // 2 KB
    int*   rangeBase = (int*)(ws + (size_t)(1 << 20) + 106496);   // 2 KB (501)
    float* inv       = (float*)(ws + (size_t)( 2 << 20));     // 0.4 MB
    int2*  odpk      = (int2*)(ws + (size_t)( 3 << 20));      // 0.8 MB
    int2*  bucket    = (int2*)(ws + (size_t)( 4 << 20));      // 12.8 MB (dead after p3)
    f16*   h2s       = (f16*)bucket;                          // 12.8 MB (reuses bucket)
    int*   csr_s     = (int*)(ws + (size_t)(17 << 20));       // <=7.6 MB (padded)
    f16*   h0s       = (f16*)(ws + (size_t)(25 << 20));       // 12.8 MB (+row NN)
    f16*   h1s       = (f16*)(ws + (size_t)(38 << 20));       // 12.8 MB

    k_p1<<<NBK, 256, 0, stream>>>(ei, blkhist);
    k_scanR1<<<NR, 512, 0, stream>>>(blkhist, rtot);
    k_scanR2<<<1, 512, 0, stream>>>(rtot, rangeBase);
    k_p2<<<NBK, 256, 0, stream>>>(ei, blkhist, rangeBase, bucket);
    k_p3<<<NR, 256, 0, stream>>>(bucket, rangeBase, odpk, inv, csr_s);

    int gblk = (NN + 63) / 64;   // 1563 (covers zero row NN at row0=99968..100031)
    k_gemm1<<<gblk, 256, 0, stream>>>(x, W1, inv, h0s);
    k_agg1<<<NN / 4, 256, 0, stream>>>(odpk, csr_s, inv, h0s, b1, h1s);

    k_gemm2<<<gblk, 256, 0, stream>>>(h1s, W2, inv, h2s);
    k_agg2<<<NN / 4, 256, 0, stream>>>(odpk, csr_s, inv, h2s, b2, out);
}